// Round 13
// baseline (596.003 us; speedup 1.0000x reference)
//
#include <hip/hip_runtime.h>

#define NN 150000
#define EE 600000
#define HH 4
#define CC 64
#define GG 4096
#define INF 9

typedef __attribute__((ext_vector_type(8))) short bf16x8;
typedef __attribute__((ext_vector_type(4))) float f32x4;

__device__ __forceinline__ float lrelu(float a){ return a > 0.f ? a : 0.2f*a; }
__device__ __forceinline__ float b2f(unsigned short u){ return __uint_as_float((unsigned)u << 16); }
__device__ __forceinline__ unsigned short f2b(float f){
  unsigned u = __float_as_uint(f);
  return (unsigned short)((u + 0x7fff + ((u >> 16) & 1)) >> 16);   // RNE
}

// ---------------- CSR build ----------------
__global__ __launch_bounds__(256) void k_count(const int* __restrict__ dst, int* __restrict__ deg){
  int e = blockIdx.x*256 + threadIdx.x;
  if (e < EE) atomicAdd(&deg[dst[e]], 1);
}

__global__ __launch_bounds__(256) void k_scan1(const int* __restrict__ deg, int* __restrict__ excl, int* __restrict__ bsum){
  __shared__ int s[256];
  int tid = threadIdx.x, gid = blockIdx.x*256 + tid;
  int v = (gid < NN) ? deg[gid] : 0;
  s[tid] = v; __syncthreads();
  for (int off = 1; off < 256; off <<= 1){
    int t = (tid >= off) ? s[tid-off] : 0; __syncthreads();
    s[tid] += t; __syncthreads();
  }
  if (gid < NN) excl[gid] = s[tid] - v;
  if (tid == 255) bsum[blockIdx.x] = s[255];
}

__global__ __launch_bounds__(1024) void k_scan2(int* __restrict__ bsum, int nb){
  __shared__ int s[1024];
  int tid = threadIdx.x;
  int v = (tid < nb) ? bsum[tid] : 0;
  s[tid] = v; __syncthreads();
  for (int off = 1; off < 1024; off <<= 1){
    int t = (tid >= off) ? s[tid-off] : 0; __syncthreads();
    s[tid] += t; __syncthreads();
  }
  if (tid < nb) bsum[tid] = s[tid] - v;
}

__global__ __launch_bounds__(256) void k_scan3(int* __restrict__ rp, const int* __restrict__ bsum){
  int gid = blockIdx.x*256 + threadIdx.x;
  if (gid < NN) rp[gid] += bsum[blockIdx.x];
  if (gid == 0) rp[NN] = EE;
}

__global__ __launch_bounds__(256) void k_fill(const int* __restrict__ src, const int* __restrict__ dst,
                                              const int* __restrict__ rp, int* __restrict__ fill,
                                              int* __restrict__ col){
  int e = blockIdx.x*256 + threadIdx.x;
  if (e < EE){
    int d = dst[e];
    int pos = rp[d] + atomicAdd(&fill[d], 1);
    col[pos] = src[e];
  }
}

__global__ __launch_bounds__(256) void k_gstart(const int* __restrict__ batch, int* __restrict__ gstart){
  int g = blockIdx.x*256 + threadIdx.x;
  if (g > GG) return;
  int lo = 0, hi = NN;
  while (lo < hi){ int mid = (lo+hi) >> 1; if (batch[mid] < g) lo = mid+1; else hi = mid; }
  gstart[g] = lo;
}

// ---------------- fold weights (logits folds + layer-0 stack) ----------------
__global__ __launch_bounds__(256) void k_fold(const float* __restrict__ g0W, const float* __restrict__ g0as,
    const float* __restrict__ g0ad, const float* __restrict__ gW, const float* __restrict__ gas,
    const float* __restrict__ gad, float* __restrict__ Wa0, float* __restrict__ Wa,
    float* __restrict__ Wstk0){
  const int OFF1 = 72, OFF2 = OFF1 + 1536, OFF3 = OFF2 + 2304;
  int t = blockIdx.x*256 + threadIdx.x;
  if (t < OFF1){
    int k = t >> 3, j = t & 7, h = j & 3;
    const float* a = (j < 4) ? g0as : g0ad;
    float s = 0.f;
    for (int c = 0; c < 64; c++) s += g0W[k*256 + h*64 + c] * a[h*64 + c];
    Wa0[t] = s;
  } else if (t < OFF2){
    int u = t - OFF1;
    int i = u / 512, r = u % 512, k = r >> 3, j = r & 7, h = j & 3;
    const float* a = ((j < 4) ? gas : gad) + (size_t)i*256;
    float s = 0.f;
    for (int c = 0; c < 64; c++) s += gW[(size_t)i*16384 + k*256 + h*64 + c] * a[h*64 + c];
    Wa[u] = s;
  } else if (t < OFF3){
    int u = t - OFF2;           // u = k*64 + j, k = h*9+c
    int k = u >> 6, j = u & 63;
    int h = k / 9, c = k - h*9;
    Wstk0[u] = 0.25f * g0W[c*256 + h*64 + j];
  }
}

// ---------------- fold W into MFMA fragment order, split bf16 hi/lo ----------------
__global__ __launch_bounds__(256) void k_foldB(const float* __restrict__ gW,
    unsigned short* __restrict__ Wfhi, unsigned short* __restrict__ Wflo){
  int t = blockIdx.x*256 + threadIdx.x;
  if (t >= 3*4*8*64) return;
  int l = t & 63, s = (t >> 6) & 7, c = (t >> 9) & 3, i = t >> 11;
  size_t base = (size_t)i*16384 + (size_t)(((c*8 + s)*64 + l))*8;
  #pragma unroll
  for (int b = 0; b < 8; b++){
    int k = s*32 + ((l >> 4) << 3) + b;
    int h = k >> 6, ci = k & 63;
    int j = (c << 4) + (l & 15);
    float v = 0.25f * gW[(size_t)i*16384 + ci*256 + h*64 + j];
    unsigned short hi = f2b(v);
    unsigned short lo = f2b(v - b2f(hi));
    Wfhi[base + b] = hi;
    Wflo[base + b] = lo;
  }
}

// ---------------- logits (layer 0 only) ----------------
__global__ __launch_bounds__(256) void k_logits9(const float* __restrict__ hin, const float* __restrict__ Wa,
                                                 float* __restrict__ lg){
  int idx = blockIdx.x*256 + threadIdx.x;
  int node = idx >> 3, j = idx & 7;
  if (node >= NN) return;
  const float* r = hin + (size_t)node*INF;
  float s = 0.f;
  #pragma unroll
  for (int k = 0; k < INF; k++) s += r[k] * Wa[k*8 + j];
  lg[(size_t)node*8 + j] = s;
}

// ---------------- fused edge weights + normalization (thread per (node,head)) ----------------
__global__ __launch_bounds__(256) void k_wgt(const float* __restrict__ lg, const int* __restrict__ rp,
    const int* __restrict__ col, float* __restrict__ w, float* __restrict__ wself){
  int t = blockIdx.x*256 + threadIdx.x;
  if (t >= NN*4) return;
  int n = t >> 2, h = t & 3;
  float edv = lg[(size_t)n*8 + 4 + h];
  int rb = rp[n], re = rp[n+1];
  float s = 0.f;
  for (int p = rb; p < re; p++){
    float e = __expf(lrelu(lg[(size_t)col[p]*8 + h] + edv));
    w[(size_t)p*4 + h] = e;
    s += e;
  }
  float wsf = __expf(lrelu(lg[(size_t)n*8 + h] + edv));
  float inv = 1.f / (s + wsf);
  for (int p = rb; p < re; p++) w[(size_t)p*4 + h] *= inv;
  wself[t] = wsf * inv;
}

// ---------------- layer-0 aggregation (wave per node, f32, batch-8) ----------------
__global__ __launch_bounds__(256) void k_agg9(const float* __restrict__ hin, const float* __restrict__ w,
     const float* __restrict__ wself, const int* __restrict__ rp, const int* __restrict__ col,
     float* __restrict__ aggo){
  int node = (blockIdx.x*256 + threadIdx.x) >> 6;
  int lane = threadIdx.x & 63;
  if (node >= NN) return;
  node = __builtin_amdgcn_readfirstlane(node);
  int rb = rp[node], re = rp[node+1];
  float4 ws4 = *(const float4*)(wself + (size_t)node*4);
  float xself = (lane < INF) ? hin[(size_t)node*INF + lane] : 0.f;
  float acc[4] = {ws4.x*xself, ws4.y*xself, ws4.z*xself, ws4.w*xself};

  int last = re - 1;
  for (int e = rb; e < re; e += 8){
    int ec[8], sidx[8]; float4 wv[8]; float xv[8];
    #pragma unroll
    for (int q = 0; q < 8; q++){ int eq = e + q; ec[q] = (eq <= last) ? eq : last; }
    #pragma unroll
    for (int q = 0; q < 8; q++) sidx[q] = col[ec[q]];
    #pragma unroll
    for (int q = 0; q < 8; q++) wv[q] = *(const float4*)(w + (size_t)ec[q]*4);
    #pragma unroll
    for (int q = 0; q < 8; q++)
      xv[q] = (lane < INF) ? hin[(size_t)sidx[q]*INF + lane] : 0.f;
    int n = re - e;
    #pragma unroll
    for (int q = 0; q < 8; q++){
      if (q < n){
        acc[0] += wv[q].x*xv[q]; acc[1] += wv[q].y*xv[q];
        acc[2] += wv[q].z*xv[q]; acc[3] += wv[q].w*xv[q];
      }
    }
  }

  if (lane < INF){
    float* ap = aggo + (size_t)node*36 + lane;
    ap[0] = acc[0]; ap[INF] = acc[1]; ap[2*INF] = acc[2]; ap[3*INF] = acc[3];
  }
}

// ---------------- layer-0 transform (f32, VALU) + epilogue + layer-1 logits ----------------
__global__ __launch_bounds__(256, 4) void k_gemmB36(const float* __restrict__ agg, const float* __restrict__ Ws,
    const float* __restrict__ bias, const float* __restrict__ gma, const float* __restrict__ bta,
    const float* __restrict__ mea, const float* __restrict__ var,
    float* __restrict__ hout, unsigned short* __restrict__ hbf,
    const float* __restrict__ WaN, float* __restrict__ lg){
  __shared__ float xs[64*68];
  __shared__ float ws[64*68];
  __shared__ float wal[512];
  int t = threadIdx.x;
  int base = blockIdx.x * 64;
  int r = t >> 4, c2 = t & 15;
  for (int i = t; i < 512; i += 256) wal[i] = WaN[i];

  for (int i = t; i < 64*9; i += 256){
    int nd = i / 9, kk = i - nd*9;
    float4 v = {0.f,0.f,0.f,0.f};
    if (base + nd < NN) v = *(const float4*)(agg + (size_t)(base+nd)*36 + kk*4);
    *(float4*)(xs + nd*44 + kk*4) = v;
  }
  for (int i = t; i < 36*16; i += 256){
    int k = i >> 4, c4 = i & 15;
    *(float4*)(ws + k*68 + c4*4) = *(const float4*)(Ws + (size_t)k*64 + c4*4);
  }
  __syncthreads();

  float acc[4][4];
  #pragma unroll
  for (int i = 0; i < 4; i++)
    #pragma unroll
    for (int u = 0; u < 4; u++) acc[i][u] = 0.f;

  #pragma unroll 2
  for (int k4 = 0; k4 < 36; k4 += 4){
    float4 xv[4], wv[4];
    #pragma unroll
    for (int i = 0; i < 4; i++) xv[i] = *(const float4*)(xs + (4*r+i)*44 + k4);
    #pragma unroll
    for (int u = 0; u < 4; u++) wv[u] = *(const float4*)(ws + (k4+u)*68 + 4*c2);
    #pragma unroll
    for (int i = 0; i < 4; i++){
      float xr[4] = {xv[i].x, xv[i].y, xv[i].z, xv[i].w};
      #pragma unroll
      for (int u = 0; u < 4; u++){
        acc[i][0] += xr[u]*wv[u].x; acc[i][1] += xr[u]*wv[u].y;
        acc[i][2] += xr[u]*wv[u].z; acc[i][3] += xr[u]*wv[u].w;
      }
    }
  }

  __syncthreads();
  int cb = 4*c2;
  float4 bi = *(const float4*)(bias + cb);
  float4 gm = *(const float4*)(gma + cb);
  float4 bt = *(const float4*)(bta + cb);
  float4 me = *(const float4*)(mea + cb);
  float4 va = *(const float4*)(var + cb);
  float sc0 = rsqrtf(va.x + 1e-5f)*gm.x, sc1 = rsqrtf(va.y + 1e-5f)*gm.y;
  float sc2 = rsqrtf(va.z + 1e-5f)*gm.z, sc3 = rsqrtf(va.w + 1e-5f)*gm.w;
  #pragma unroll
  for (int i = 0; i < 4; i++){
    int node = base + 4*r + i;
    if (node < NN){
      float o0 = (acc[i][0] + bi.x - me.x)*sc0 + bt.x;
      float o1 = (acc[i][1] + bi.y - me.y)*sc1 + bt.y;
      float o2 = (acc[i][2] + bi.z - me.z)*sc2 + bt.z;
      float o3 = (acc[i][3] + bi.w - me.w)*sc3 + bt.w;
      o0 = o0 > 0.f ? o0 : (__expf(o0) - 1.f);
      o1 = o1 > 0.f ? o1 : (__expf(o1) - 1.f);
      o2 = o2 > 0.f ? o2 : (__expf(o2) - 1.f);
      o3 = o3 > 0.f ? o3 : (__expf(o3) - 1.f);
      float4 st = {o0, o1, o2, o3};
      *(float4*)(hout + (size_t)node*64 + cb) = st;
      uint2 pb = { (unsigned)f2b(o0) | ((unsigned)f2b(o1) << 16),
                   (unsigned)f2b(o2) | ((unsigned)f2b(o3) << 16) };
      *(uint2*)(hbf + (size_t)node*64 + cb) = pb;
      *(float4*)(xs + (4*r+i)*68 + cb) = st;
    }
  }
  __syncthreads();
  int nd = t >> 2, jq = (t & 3) * 2;
  int node = base + nd;
  if (node < NN){
    float s0 = 0.f, s1 = 0.f;
    #pragma unroll 4
    for (int k = 0; k < 64; k += 4){
      float4 xv = *(const float4*)(xs + nd*68 + k);
      const float* w0 = wal + k*8 + jq;
      s0 += xv.x*w0[0] + xv.y*w0[8] + xv.z*w0[16] + xv.w*w0[24];
      s1 += xv.x*w0[1] + xv.y*w0[9] + xv.z*w0[17] + xv.w*w0[25];
    }
    float2 sv = {s0, s1};
    *(float2*)(lg + (size_t)node*8 + jq) = sv;
  }
}

// ---------------- layers 1-3 FUSED: aggregate (LDS) + MFMA transform + epilogue + logits ----------------
// 64 nodes/block, 4 waves. Wave w owns nodes base+16w..+15 and a private LDS region
// (16 rows x 264 ushorts, aggb fragment layout, padded stride vs 256 for bank spread).
// Phase A: agg4b-style aggregation (4 passes x 4 nodes/wave) -> bf16 LDS rows.
// Phase B: MFMA fragments read from own LDS rows (b128, 2-way-free banks); B = Wfhi/Wflo global.
// D scattered back into own region as f32 [16][68]; BN/ELU/residual epilogue; next-layer logits.
// hbin/hbout ping-pong (cross-block gather vs own-row write).
template<bool LOGITS>
__global__ __launch_bounds__(256, 4) void k_fuse(const unsigned short* __restrict__ hbin,
    const float* __restrict__ w, const float* __restrict__ wself,
    const int* __restrict__ rp, const int* __restrict__ col,
    const unsigned short* __restrict__ Wfhi, const unsigned short* __restrict__ Wflo,
    const float* __restrict__ bias, const float* __restrict__ gma, const float* __restrict__ bta,
    const float* __restrict__ mea, const float* __restrict__ var,
    const float* __restrict__ hres, float* __restrict__ hout, unsigned short* __restrict__ hbout,
    const float* __restrict__ WaN, float* __restrict__ lg){
  __shared__ unsigned short al[64*264];   // 33.8 KB
  __shared__ float wal[512];
  int t = threadIdx.x, lane = t & 63, wv = t >> 6;
  int base = blockIdx.x * 64;
  if (LOGITS){ for (int i = t; i < 512; i += 256) wal[i] = WaN[i]; }

  // ---- phase A: aggregate 16 nodes per wave into LDS (bf16, fragment layout) ----
  {
    int ns = lane >> 4, q = lane & 15;
    for (int p = 0; p < 4; p++){
      int nd = wv*16 + p*4 + ns;
      int node = base + nd;
      unsigned short* arow = al + (size_t)nd*264;
      int rb = 0, re = 0;
      if (node < NN){ rb = rp[node]; re = rp[node+1]; }
      int d = re - rb;
      d = max(d, __shfl_xor(d, 16));
      d = max(d, __shfl_xor(d, 32));
      float acc[4][4];
      {
        float4 ws4 = {0.f,0.f,0.f,0.f};
        float x0=0.f, x1=0.f, x2=0.f, x3=0.f;
        if (node < NN){
          ws4 = *(const float4*)(wself + (size_t)node*4);
          ushort4 xu = *(const ushort4*)(hbin + (size_t)node*64 + q*4);
          x0 = b2f(xu.x); x1 = b2f(xu.y); x2 = b2f(xu.z); x3 = b2f(xu.w);
        }
        #pragma unroll
        for (int h = 0; h < 4; h++){
          float wh = (h==0)?ws4.x:(h==1)?ws4.y:(h==2)?ws4.z:ws4.w;
          acc[h][0] = wh*x0; acc[h][1] = wh*x1; acc[h][2] = wh*x2; acc[h][3] = wh*x3;
        }
      }
      for (int i2 = 0; i2 < d; i2 += 2){
        int e0 = rb + i2, e1 = rb + i2 + 1;
        if (e0 < re){
          int s0 = col[e0];
          float4 w0 = *(const float4*)(w + (size_t)e0*4);
          ushort4 u0 = *(const ushort4*)(hbin + (size_t)s0*64 + q*4);
          float y0=b2f(u0.x), y1=b2f(u0.y), y2=b2f(u0.z), y3=b2f(u0.w);
          acc[0][0]+=w0.x*y0; acc[0][1]+=w0.x*y1; acc[0][2]+=w0.x*y2; acc[0][3]+=w0.x*y3;
          acc[1][0]+=w0.y*y0; acc[1][1]+=w0.y*y1; acc[1][2]+=w0.y*y2; acc[1][3]+=w0.y*y3;
          acc[2][0]+=w0.z*y0; acc[2][1]+=w0.z*y1; acc[2][2]+=w0.z*y2; acc[2][3]+=w0.z*y3;
          acc[3][0]+=w0.w*y0; acc[3][1]+=w0.w*y1; acc[3][2]+=w0.w*y2; acc[3][3]+=w0.w*y3;
        }
        if (e1 < re){
          int s1 = col[e1];
          float4 w1 = *(const float4*)(w + (size_t)e1*4);
          ushort4 u1 = *(const ushort4*)(hbin + (size_t)s1*64 + q*4);
          float y0=b2f(u1.x), y1=b2f(u1.y), y2=b2f(u1.z), y3=b2f(u1.w);
          acc[0][0]+=w1.x*y0; acc[0][1]+=w1.x*y1; acc[0][2]+=w1.x*y2; acc[0][3]+=w1.x*y3;
          acc[1][0]+=w1.y*y0; acc[1][1]+=w1.y*y1; acc[1][2]+=w1.y*y2; acc[1][3]+=w1.y*y3;
          acc[2][0]+=w1.z*y0; acc[2][1]+=w1.z*y1; acc[2][2]+=w1.z*y2; acc[2][3]+=w1.z*y3;
          acc[3][0]+=w1.w*y0; acc[3][1]+=w1.w*y1; acc[3][2]+=w1.w*y2; acc[3][3]+=w1.w*y3;
        }
      }
      #pragma unroll
      for (int h = 0; h < 4; h++){
        ushort4 o = { f2b(acc[h][0]), f2b(acc[h][1]), f2b(acc[h][2]), f2b(acc[h][3]) };
        *(ushort4*)(arow + h*64 + q*4) = o;
      }
    }
  }
  __syncthreads();

  // ---- phase B: MFMA from own LDS rows ----
  int arow_i = wv*16 + (lane & 15);
  const unsigned short* ap = al + (size_t)arow_i*264 + ((lane >> 4) << 3);
  bf16x8 af[8];
  #pragma unroll
  for (int s = 0; s < 8; s++) af[s] = *(const bf16x8*)(ap + s*32);

  f32x4 acch[4], accl[4];
  #pragma unroll
  for (int c = 0; c < 4; c++){ acch[c] = (f32x4)0.f; accl[c] = (f32x4)0.f; }

  #pragma unroll
  for (int s = 0; s < 8; s++){
    #pragma unroll
    for (int c = 0; c < 4; c++){
      int fidx = ((c*8 + s)*64 + lane)*8;
      bf16x8 bh = *(const bf16x8*)(Wfhi + fidx);
      bf16x8 bl = *(const bf16x8*)(Wflo + fidx);
      acch[c] = __builtin_amdgcn_mfma_f32_16x16x32_bf16(af[s], bh, acch[c], 0, 0, 0);
      accl[c] = __builtin_amdgcn_mfma_f32_16x16x32_bf16(af[s], bl, accl[c], 0, 0, 0);
    }
  }

  // ---- D scatter into own region, reinterpreted f32 [16][68] ----
  float* df = (float*)(al + (size_t)wv*16*264);
  {
    int rr = ((lane >> 4) << 2), cc = lane & 15;
    #pragma unroll
    for (int c = 0; c < 4; c++)
      #pragma unroll
      for (int r = 0; r < 4; r++)
        df[(rr + r)*68 + (c << 4) + cc] = acch[c][r] + accl[c][r];
  }
  __syncthreads();

  // ---- epilogue: bias + BN + ELU + residual (own 16 nodes) ----
  {
    int j = lane;
    float bi = bias[j], bt2 = bta[j], me = mea[j];
    float sc = rsqrtf(var[j] + 1e-5f) * gma[j];
    #pragma unroll 4
    for (int it = 0; it < 16; it++){
      int node = base + wv*16 + it;
      if (node < NN){
        float o = df[it*68 + j] + bi;
        o = (o - me)*sc + bt2;
        o = o > 0.f ? o : (__expf(o) - 1.f);
        o += hres[(size_t)node*64 + j];
        hout[(size_t)node*64 + j] = o;
        if (LOGITS){
          hbout[(size_t)node*64 + j] = f2b(o);
          df[it*68 + j] = o;
        }
      }
    }
  }
  if (LOGITS){
    __syncthreads();
    int nd = lane >> 2, jq = (lane & 3) * 2;
    int node = base + wv*16 + nd;
    if (node < NN){
      float s0 = 0.f, s1 = 0.f;
      #pragma unroll 4
      for (int k = 0; k < 64; k += 4){
        float4 xv = *(const float4*)(df + nd*68 + k);
        const float* w0 = wal + k*8 + jq;
        s0 += xv.x*w0[0] + xv.y*w0[8] + xv.z*w0[16] + xv.w*w0[24];
        s1 += xv.x*w0[1] + xv.y*w0[9] + xv.z*w0[17] + xv.w*w0[25];
      }
      float2 sv = {s0, s1};
      *(float2*)(lg + (size_t)node*8 + jq) = sv;
    }
  }
}

// ---------------- pooling ----------------
__global__ __launch_bounds__(64) void k_pool(const float* __restrict__ h, const int* __restrict__ gstart,
                                             float* __restrict__ pooled){
  int g = blockIdx.x; int lane = threadIdx.x;
  int beg = gstart[g], end = gstart[g+1];
  float acc = 0.f;
  for (int n = beg; n < end; n++) acc += h[(size_t)n*64 + lane];
  float cnt = (float)(end - beg);
  pooled[(size_t)g*64 + lane] = acc / fmaxf(cnt, 1.f);
}

// ---------------- output MLP (wave per graph) ----------------
__global__ __launch_bounds__(256) void k_mlp(const float* __restrict__ pooled, const float* __restrict__ W1,
                                             const float* __restrict__ b1, const float* __restrict__ W2,
                                             const float* __restrict__ b2, float* __restrict__ out){
  int g = (blockIdx.x*256 + threadIdx.x) >> 6;
  int lane = threadIdx.x & 63;
  if (g >= GG) return;
  float pv = pooled[(size_t)g*64 + lane];
  int j = lane & 31, half = lane >> 5;
  float z = half ? 0.f : b1[j];
  #pragma unroll
  for (int c = 0; c < 32; c++){
    int cc = half*32 + c;
    z += __shfl(pv, cc) * W1[cc*32 + j];
  }
  z += __shfl_xor(z, 32);
  float o = 0.f;
  if (half == 0){
    z = z > 0.f ? z : (__expf(z) - 1.f);
    o = z * W2[j];
  }
  o += __shfl_xor(o, 1); o += __shfl_xor(o, 2); o += __shfl_xor(o, 4);
  o += __shfl_xor(o, 8); o += __shfl_xor(o, 16);
  if (lane == 0) out[g] = o + b2[0];
}

extern "C" void kernel_launch(void* const* d_in, const int* in_sizes, int n_in,
                              void* d_out, int out_size, void* d_ws, size_t ws_size,
                              hipStream_t stream) {
  const float* x    = (const float*)d_in[0];
  const int*   ei   = (const int*)d_in[1];
  const int*   batch= (const int*)d_in[2];
  const float* g0W  = (const float*)d_in[3];
  const float* g0as = (const float*)d_in[4];
  const float* g0ad = (const float*)d_in[5];
  const float* g0b  = (const float*)d_in[6];
  const float* bn0g = (const float*)d_in[7];
  const float* bn0b = (const float*)d_in[8];
  const float* bn0m = (const float*)d_in[9];
  const float* bn0v = (const float*)d_in[10];
  const float* gW   = (const float*)d_in[11];
  const float* gas  = (const float*)d_in[12];
  const float* gad  = (const float*)d_in[13];
  const float* gb   = (const float*)d_in[14];
  const float* bng  = (const float*)d_in[15];
  const float* bnb  = (const float*)d_in[16];
  const float* bnm  = (const float*)d_in[17];
  const float* bnv  = (const float*)d_in[18];
  const float* W1   = (const float*)d_in[19];
  const float* b1   = (const float*)d_in[20];
  const float* W2   = (const float*)d_in[21];
  const float* b2   = (const float*)d_in[22];
  float* out = (float*)d_out;
  (void)in_sizes; (void)n_in; (void)out_size; (void)ws_size;

  char* base = (char*)d_ws; size_t off = 0;
  auto alloc = [&](size_t b)->void*{ void* p = base + off; off = (off + b + 255) & ~(size_t)255; return p; };
  float* agg32  = (float*)alloc((size_t)NN*36*4);                   // 21.6 MB
  float* h_cur  = (float*)alloc((size_t)NN*64*4);                   // 38.4 MB
  unsigned short* hbfA = (unsigned short*)alloc((size_t)NN*64*2);   // 19.2 MB
  unsigned short* hbfB = (unsigned short*)alloc((size_t)NN*64*2);   // 19.2 MB
  float* lg     = (float*)alloc((size_t)NN*8*4);                    // 4.8 MB
  float* wE     = (float*)alloc((size_t)EE*4*4);                    // 9.6 MB
  float* wS     = (float*)alloc((size_t)NN*4*4);                    // 2.4 MB
  int*   deg    = (int*)alloc((size_t)NN*4);
  int*   fill   = (int*)alloc((size_t)NN*4);
  int*   rp     = (int*)alloc((size_t)(NN+1)*4);
  int*   col    = (int*)alloc((size_t)EE*4);
  int*   bsum   = (int*)alloc(1024*4);
  int*   gstart = (int*)alloc((size_t)(GG+1)*4);
  float* pooled = (float*)alloc((size_t)GG*64*4);
  float* Wa0    = (float*)alloc((size_t)72*4);
  float* Wa     = (float*)alloc((size_t)1536*4);
  float* Wstk0  = (float*)alloc((size_t)2304*4);
  unsigned short* Wfhi = (unsigned short*)alloc((size_t)3*16384*2);
  unsigned short* Wflo = (unsigned short*)alloc((size_t)3*16384*2);

  const int* esrc = ei;
  const int* edst = ei + EE;

  hipMemsetAsync(deg, 0, (size_t)NN*4, stream);
  hipMemsetAsync(fill, 0, (size_t)NN*4, stream);

  int nb1 = (NN + 255)/256;
  k_count<<<(EE+255)/256, 256, 0, stream>>>(edst, deg);
  k_scan1<<<nb1, 256, 0, stream>>>(deg, rp, bsum);
  k_scan2<<<1, 1024, 0, stream>>>(bsum, nb1);
  k_scan3<<<nb1, 256, 0, stream>>>(rp, bsum);
  k_fill<<<(EE+255)/256, 256, 0, stream>>>(esrc, edst, rp, fill, col);
  k_gstart<<<(GG+256)/256, 256, 0, stream>>>(batch, gstart);
  k_fold<<<16, 256, 0, stream>>>(g0W, g0as, g0ad, gW, gas, gad, Wa0, Wa, Wstk0);
  k_foldB<<<24, 256, 0, stream>>>(gW, Wfhi, Wflo);

  int nlog  = (NN*8 + 255)/256;   // 4688
  int nwave = NN/4;               // 37500
  int ngB   = (NN + 63)/64;       // 2344
  int nnrm  = (NN*4 + 255)/256;   // 2344

  // layer 0 (layer-1 logits fused into gemmB36 via WaN = Wa[0])
  k_logits9<<<nlog, 256, 0, stream>>>(x, Wa0, lg);
  k_wgt<<<nnrm, 256, 0, stream>>>(lg, rp, col, wE, wS);
  k_agg9<<<nwave, 256, 0, stream>>>(x, wE, wS, rp, col, agg32);
  k_gemmB36<<<ngB, 256, 0, stream>>>(agg32, Wstk0, g0b, bn0g, bn0b, bn0m, bn0v,
                                     h_cur, hbfA, Wa, lg);
  // layers 1..3: fused agg+MFMA; hbf ping-pong A->B->A
  for (int i = 0; i < 3; i++){
    const unsigned short* hin = (i & 1) ? hbfB : hbfA;
    unsigned short* hbo       = (i & 1) ? hbfA : hbfB;
    k_wgt<<<nnrm, 256, 0, stream>>>(lg, rp, col, wE, wS);
    if (i < 2)
      k_fuse<true><<<ngB, 256, 0, stream>>>(hin, wE, wS, rp, col,
                                            Wfhi + (size_t)i*16384, Wflo + (size_t)i*16384,
                                            gb + (size_t)i*64,
                                            bng + (size_t)i*64, bnb + (size_t)i*64,
                                            bnm + (size_t)i*64, bnv + (size_t)i*64,
                                            h_cur, h_cur, hbo, Wa + (size_t)(i+1)*512, lg);
    else
      k_fuse<false><<<ngB, 256, 0, stream>>>(hin, wE, wS, rp, col,
                                             Wfhi + (size_t)i*16384, Wflo + (size_t)i*16384,
                                             gb + (size_t)i*64,
                                             bng + (size_t)i*64, bnb + (size_t)i*64,
                                             bnm + (size_t)i*64, bnv + (size_t)i*64,
                                             h_cur, h_cur, nullptr, nullptr, nullptr);
  }

  k_pool<<<GG, 64, 0, stream>>>(h_cur, gstart, pooled);
  k_mlp<<<(GG*64 + 255)/256, 256, 0, stream>>>(pooled, W1, b1, W2, b2, out);
}

// Round 14
// 514.312 us; speedup vs baseline: 1.1588x; 1.1588x over previous
//
#include <hip/hip_runtime.h>

#define NN 150000
#define EE 600000
#define HH 4
#define CC 64
#define GG 4096
#define INF 9

typedef __attribute__((ext_vector_type(8))) short bf16x8;
typedef __attribute__((ext_vector_type(4))) float f32x4;

__device__ __forceinline__ float lrelu(float a){ return a > 0.f ? a : 0.2f*a; }
__device__ __forceinline__ float b2f(unsigned short u){ return __uint_as_float((unsigned)u << 16); }
__device__ __forceinline__ unsigned short f2b(float f){
  unsigned u = __float_as_uint(f);
  return (unsigned short)((u + 0x7fff + ((u >> 16) & 1)) >> 16);   // RNE
}

// ---------------- CSR build ----------------
__global__ __launch_bounds__(256) void k_count(const int* __restrict__ dst, int* __restrict__ deg){
  int e = blockIdx.x*256 + threadIdx.x;
  if (e < EE) atomicAdd(&deg[dst[e]], 1);
}

__global__ __launch_bounds__(256) void k_scan1(const int* __restrict__ deg, int* __restrict__ excl, int* __restrict__ bsum){
  __shared__ int s[256];
  int tid = threadIdx.x, gid = blockIdx.x*256 + tid;
  int v = (gid < NN) ? deg[gid] : 0;
  s[tid] = v; __syncthreads();
  for (int off = 1; off < 256; off <<= 1){
    int t = (tid >= off) ? s[tid-off] : 0; __syncthreads();
    s[tid] += t; __syncthreads();
  }
  if (gid < NN) excl[gid] = s[tid] - v;
  if (tid == 255) bsum[blockIdx.x] = s[255];
}

__global__ __launch_bounds__(1024) void k_scan2(int* __restrict__ bsum, int nb){
  __shared__ int s[1024];
  int tid = threadIdx.x;
  int v = (tid < nb) ? bsum[tid] : 0;
  s[tid] = v; __syncthreads();
  for (int off = 1; off < 1024; off <<= 1){
    int t = (tid >= off) ? s[tid-off] : 0; __syncthreads();
    s[tid] += t; __syncthreads();
  }
  if (tid < nb) bsum[tid] = s[tid] - v;
}

__global__ __launch_bounds__(256) void k_scan3(int* __restrict__ rp, const int* __restrict__ bsum){
  int gid = blockIdx.x*256 + threadIdx.x;
  if (gid < NN) rp[gid] += bsum[blockIdx.x];
  if (gid == 0) rp[NN] = EE;
}

__global__ __launch_bounds__(256) void k_fill(const int* __restrict__ src, const int* __restrict__ dst,
                                              const int* __restrict__ rp, int* __restrict__ fill,
                                              int* __restrict__ col){
  int e = blockIdx.x*256 + threadIdx.x;
  if (e < EE){
    int d = dst[e];
    int pos = rp[d] + atomicAdd(&fill[d], 1);
    col[pos] = src[e];
  }
}

__global__ __launch_bounds__(256) void k_gstart(const int* __restrict__ batch, int* __restrict__ gstart){
  int g = blockIdx.x*256 + threadIdx.x;
  if (g > GG) return;
  int lo = 0, hi = NN;
  while (lo < hi){ int mid = (lo+hi) >> 1; if (batch[mid] < g) lo = mid+1; else hi = mid; }
  gstart[g] = lo;
}

// ---------------- fold weights (logits folds + layer-0 stack) ----------------
__global__ __launch_bounds__(256) void k_fold(const float* __restrict__ g0W, const float* __restrict__ g0as,
    const float* __restrict__ g0ad, const float* __restrict__ gW, const float* __restrict__ gas,
    const float* __restrict__ gad, float* __restrict__ Wa0, float* __restrict__ Wa,
    float* __restrict__ Wstk0){
  const int OFF1 = 72, OFF2 = OFF1 + 1536, OFF3 = OFF2 + 2304;
  int t = blockIdx.x*256 + threadIdx.x;
  if (t < OFF1){
    int k = t >> 3, j = t & 7, h = j & 3;
    const float* a = (j < 4) ? g0as : g0ad;
    float s = 0.f;
    for (int c = 0; c < 64; c++) s += g0W[k*256 + h*64 + c] * a[h*64 + c];
    Wa0[t] = s;
  } else if (t < OFF2){
    int u = t - OFF1;
    int i = u / 512, r = u % 512, k = r >> 3, j = r & 7, h = j & 3;
    const float* a = ((j < 4) ? gas : gad) + (size_t)i*256;
    float s = 0.f;
    for (int c = 0; c < 64; c++) s += gW[(size_t)i*16384 + k*256 + h*64 + c] * a[h*64 + c];
    Wa[u] = s;
  } else if (t < OFF3){
    int u = t - OFF2;           // u = k*64 + j, k = h*9+c
    int k = u >> 6, j = u & 63;
    int h = k / 9, c = k - h*9;
    Wstk0[u] = 0.25f * g0W[c*256 + h*64 + j];
  }
}

// ---------------- fold W into MFMA fragment order, split bf16 hi/lo ----------------
__global__ __launch_bounds__(256) void k_foldB(const float* __restrict__ gW,
    unsigned short* __restrict__ Wfhi, unsigned short* __restrict__ Wflo){
  int t = blockIdx.x*256 + threadIdx.x;
  if (t >= 3*4*8*64) return;
  int l = t & 63, s = (t >> 6) & 7, c = (t >> 9) & 3, i = t >> 11;
  size_t base = (size_t)i*16384 + (size_t)(((c*8 + s)*64 + l))*8;
  #pragma unroll
  for (int b = 0; b < 8; b++){
    int k = s*32 + ((l >> 4) << 3) + b;
    int h = k >> 6, ci = k & 63;
    int j = (c << 4) + (l & 15);
    float v = 0.25f * gW[(size_t)i*16384 + ci*256 + h*64 + j];
    unsigned short hi = f2b(v);
    unsigned short lo = f2b(v - b2f(hi));
    Wfhi[base + b] = hi;
    Wflo[base + b] = lo;
  }
}

// ---------------- logits (layer 0 only) ----------------
__global__ __launch_bounds__(256) void k_logits9(const float* __restrict__ hin, const float* __restrict__ Wa,
                                                 float* __restrict__ lg){
  int idx = blockIdx.x*256 + threadIdx.x;
  int node = idx >> 3, j = idx & 7;
  if (node >= NN) return;
  const float* r = hin + (size_t)node*INF;
  float s = 0.f;
  #pragma unroll
  for (int k = 0; k < INF; k++) s += r[k] * Wa[k*8 + j];
  lg[(size_t)node*8 + j] = s;
}

// ---------------- fused edge weights + normalization (thread per (node,head)) ----------------
__global__ __launch_bounds__(256) void k_wgt(const float* __restrict__ lg, const int* __restrict__ rp,
    const int* __restrict__ col, float* __restrict__ w, float* __restrict__ wself){
  int t = blockIdx.x*256 + threadIdx.x;
  if (t >= NN*4) return;
  int n = t >> 2, h = t & 3;
  float edv = lg[(size_t)n*8 + 4 + h];
  int rb = rp[n], re = rp[n+1];
  float s = 0.f;
  for (int p = rb; p < re; p++){
    float e = __expf(lrelu(lg[(size_t)col[p]*8 + h] + edv));
    w[(size_t)p*4 + h] = e;
    s += e;
  }
  float wsf = __expf(lrelu(lg[(size_t)n*8 + h] + edv));
  float inv = 1.f / (s + wsf);
  for (int p = rb; p < re; p++) w[(size_t)p*4 + h] *= inv;
  wself[t] = wsf * inv;
}

// ---------------- layer-0 aggregation (wave per node, f32, batch-8) ----------------
__global__ __launch_bounds__(256) void k_agg9(const float* __restrict__ hin, const float* __restrict__ w,
     const float* __restrict__ wself, const int* __restrict__ rp, const int* __restrict__ col,
     float* __restrict__ aggo){
  int node = (blockIdx.x*256 + threadIdx.x) >> 6;
  int lane = threadIdx.x & 63;
  if (node >= NN) return;
  node = __builtin_amdgcn_readfirstlane(node);
  int rb = rp[node], re = rp[node+1];
  float4 ws4 = *(const float4*)(wself + (size_t)node*4);
  float xself = (lane < INF) ? hin[(size_t)node*INF + lane] : 0.f;
  float acc[4] = {ws4.x*xself, ws4.y*xself, ws4.z*xself, ws4.w*xself};

  int last = re - 1;
  for (int e = rb; e < re; e += 8){
    int ec[8], sidx[8]; float4 wv[8]; float xv[8];
    #pragma unroll
    for (int q = 0; q < 8; q++){ int eq = e + q; ec[q] = (eq <= last) ? eq : last; }
    #pragma unroll
    for (int q = 0; q < 8; q++) sidx[q] = col[ec[q]];
    #pragma unroll
    for (int q = 0; q < 8; q++) wv[q] = *(const float4*)(w + (size_t)ec[q]*4);
    #pragma unroll
    for (int q = 0; q < 8; q++)
      xv[q] = (lane < INF) ? hin[(size_t)sidx[q]*INF + lane] : 0.f;
    int n = re - e;
    #pragma unroll
    for (int q = 0; q < 8; q++){
      if (q < n){
        acc[0] += wv[q].x*xv[q]; acc[1] += wv[q].y*xv[q];
        acc[2] += wv[q].z*xv[q]; acc[3] += wv[q].w*xv[q];
      }
    }
  }

  if (lane < INF){
    float* ap = aggo + (size_t)node*36 + lane;
    ap[0] = acc[0]; ap[INF] = acc[1]; ap[2*INF] = acc[2]; ap[3*INF] = acc[3];
  }
}

// ---------------- layers 1-3 aggregation: 4 nodes per wave (bf16) ----------------
__global__ __launch_bounds__(256) void k_agg4b(const unsigned short* __restrict__ hb,
     const float* __restrict__ w, const float* __restrict__ wself, const int* __restrict__ rp,
     const int* __restrict__ col, unsigned short* __restrict__ aggb){
  int wv_id = (blockIdx.x*256 + threadIdx.x) >> 6;
  int lane = threadIdx.x & 63;
  int ns = lane >> 4, q = lane & 15;
  int node = wv_id*4 + ns;
  if (node >= NN) return;
  int rb = rp[node], re = rp[node+1];

  float4 ws4 = *(const float4*)(wself + (size_t)node*4);
  ushort4 xu = *(const ushort4*)(hb + (size_t)node*64 + q*4);
  float x0 = b2f(xu.x), x1 = b2f(xu.y), x2 = b2f(xu.z), x3 = b2f(xu.w);
  float acc[4][4];
  #pragma unroll
  for (int h = 0; h < 4; h++){
    float wh = (h==0)?ws4.x:(h==1)?ws4.y:(h==2)?ws4.z:ws4.w;
    acc[h][0] = wh*x0; acc[h][1] = wh*x1; acc[h][2] = wh*x2; acc[h][3] = wh*x3;
  }

  int d = re - rb;
  d = max(d, __shfl_xor(d, 16));
  d = max(d, __shfl_xor(d, 32));

  for (int i = 0; i < d; i += 2){
    int e0 = rb + i, e1 = rb + i + 1;
    bool v0 = e0 < re, v1 = e1 < re;
    if (v0){
      int s0 = col[e0];
      float4 w0 = *(const float4*)(w + (size_t)e0*4);
      ushort4 u0 = *(const ushort4*)(hb + (size_t)s0*64 + q*4);
      float y0 = b2f(u0.x), y1 = b2f(u0.y), y2 = b2f(u0.z), y3 = b2f(u0.w);
      acc[0][0] += w0.x*y0; acc[0][1] += w0.x*y1; acc[0][2] += w0.x*y2; acc[0][3] += w0.x*y3;
      acc[1][0] += w0.y*y0; acc[1][1] += w0.y*y1; acc[1][2] += w0.y*y2; acc[1][3] += w0.y*y3;
      acc[2][0] += w0.z*y0; acc[2][1] += w0.z*y1; acc[2][2] += w0.z*y2; acc[2][3] += w0.z*y3;
      acc[3][0] += w0.w*y0; acc[3][1] += w0.w*y1; acc[3][2] += w0.w*y2; acc[3][3] += w0.w*y3;
    }
    if (v1){
      int s1 = col[e1];
      float4 w1 = *(const float4*)(w + (size_t)e1*4);
      ushort4 u1 = *(const ushort4*)(hb + (size_t)s1*64 + q*4);
      float y0 = b2f(u1.x), y1 = b2f(u1.y), y2 = b2f(u1.z), y3 = b2f(u1.w);
      acc[0][0] += w1.x*y0; acc[0][1] += w1.x*y1; acc[0][2] += w1.x*y2; acc[0][3] += w1.x*y3;
      acc[1][0] += w1.y*y0; acc[1][1] += w1.y*y1; acc[1][2] += w1.y*y2; acc[1][3] += w1.y*y3;
      acc[2][0] += w1.z*y0; acc[2][1] += w1.z*y1; acc[2][2] += w1.z*y2; acc[2][3] += w1.z*y3;
      acc[3][0] += w1.w*y0; acc[3][1] += w1.w*y1; acc[3][2] += w1.w*y2; acc[3][3] += w1.w*y3;
    }
  }

  #pragma unroll
  for (int h = 0; h < 4; h++){
    ushort4 o = { f2b(acc[h][0]), f2b(acc[h][1]), f2b(acc[h][2]), f2b(acc[h][3]) };
    *(ushort4*)(aggb + (size_t)node*256 + h*64 + q*4) = o;
  }
}

// ---------------- layer-0 transform (f32, VALU) + epilogue + layer-1 logits ----------------
__global__ __launch_bounds__(256, 4) void k_gemmB36(const float* __restrict__ agg, const float* __restrict__ Ws,
    const float* __restrict__ bias, const float* __restrict__ gma, const float* __restrict__ bta,
    const float* __restrict__ mea, const float* __restrict__ var,
    float* __restrict__ hout, unsigned short* __restrict__ hbf,
    const float* __restrict__ WaN, float* __restrict__ lg){
  __shared__ float xs[64*68];
  __shared__ float ws[64*68];
  __shared__ float wal[512];
  int t = threadIdx.x;
  int base = blockIdx.x * 64;
  int r = t >> 4, c2 = t & 15;
  for (int i = t; i < 512; i += 256) wal[i] = WaN[i];

  for (int i = t; i < 64*9; i += 256){
    int nd = i / 9, kk = i - nd*9;
    float4 v = {0.f,0.f,0.f,0.f};
    if (base + nd < NN) v = *(const float4*)(agg + (size_t)(base+nd)*36 + kk*4);
    *(float4*)(xs + nd*44 + kk*4) = v;
  }
  for (int i = t; i < 36*16; i += 256){
    int k = i >> 4, c4 = i & 15;
    *(float4*)(ws + k*68 + c4*4) = *(const float4*)(Ws + (size_t)k*64 + c4*4);
  }
  __syncthreads();

  float acc[4][4];
  #pragma unroll
  for (int i = 0; i < 4; i++)
    #pragma unroll
    for (int u = 0; u < 4; u++) acc[i][u] = 0.f;

  #pragma unroll 2
  for (int k4 = 0; k4 < 36; k4 += 4){
    float4 xv[4], wv[4];
    #pragma unroll
    for (int i = 0; i < 4; i++) xv[i] = *(const float4*)(xs + (4*r+i)*44 + k4);
    #pragma unroll
    for (int u = 0; u < 4; u++) wv[u] = *(const float4*)(ws + (k4+u)*68 + 4*c2);
    #pragma unroll
    for (int i = 0; i < 4; i++){
      float xr[4] = {xv[i].x, xv[i].y, xv[i].z, xv[i].w};
      #pragma unroll
      for (int u = 0; u < 4; u++){
        acc[i][0] += xr[u]*wv[u].x; acc[i][1] += xr[u]*wv[u].y;
        acc[i][2] += xr[u]*wv[u].z; acc[i][3] += xr[u]*wv[u].w;
      }
    }
  }

  __syncthreads();
  int cb = 4*c2;
  float4 bi = *(const float4*)(bias + cb);
  float4 gm = *(const float4*)(gma + cb);
  float4 bt = *(const float4*)(bta + cb);
  float4 me = *(const float4*)(mea + cb);
  float4 va = *(const float4*)(var + cb);
  float sc0 = rsqrtf(va.x + 1e-5f)*gm.x, sc1 = rsqrtf(va.y + 1e-5f)*gm.y;
  float sc2 = rsqrtf(va.z + 1e-5f)*gm.z, sc3 = rsqrtf(va.w + 1e-5f)*gm.w;
  #pragma unroll
  for (int i = 0; i < 4; i++){
    int node = base + 4*r + i;
    if (node < NN){
      float o0 = (acc[i][0] + bi.x - me.x)*sc0 + bt.x;
      float o1 = (acc[i][1] + bi.y - me.y)*sc1 + bt.y;
      float o2 = (acc[i][2] + bi.z - me.z)*sc2 + bt.z;
      float o3 = (acc[i][3] + bi.w - me.w)*sc3 + bt.w;
      o0 = o0 > 0.f ? o0 : (__expf(o0) - 1.f);
      o1 = o1 > 0.f ? o1 : (__expf(o1) - 1.f);
      o2 = o2 > 0.f ? o2 : (__expf(o2) - 1.f);
      o3 = o3 > 0.f ? o3 : (__expf(o3) - 1.f);
      float4 st = {o0, o1, o2, o3};
      *(float4*)(hout + (size_t)node*64 + cb) = st;
      uint2 pb = { (unsigned)f2b(o0) | ((unsigned)f2b(o1) << 16),
                   (unsigned)f2b(o2) | ((unsigned)f2b(o3) << 16) };
      *(uint2*)(hbf + (size_t)node*64 + cb) = pb;
      *(float4*)(xs + (4*r+i)*68 + cb) = st;
    }
  }
  __syncthreads();
  int nd = t >> 2, jq = (t & 3) * 2;
  int node = base + nd;
  if (node < NN){
    float s0 = 0.f, s1 = 0.f;
    #pragma unroll 4
    for (int k = 0; k < 64; k += 4){
      float4 xv = *(const float4*)(xs + nd*68 + k);
      const float* w0 = wal + k*8 + jq;
      s0 += xv.x*w0[0] + xv.y*w0[8] + xv.z*w0[16] + xv.w*w0[24];
      s1 += xv.x*w0[1] + xv.y*w0[9] + xv.z*w0[17] + xv.w*w0[25];
    }
    float2 sv = {s0, s1};
    *(float2*)(lg + (size_t)node*8 + jq) = sv;
  }
}

// ---------------- layers 1-3 transform: MFMA with W staged in LDS ----------------
// 128 nodes/block, 512 threads = 8 waves. Wave wv -> nodes base+16wv..+15.
// Wfhi+Wflo (64KB) staged once per block into LDS wbuf, shared by all 8 waves;
// MFMA B-operands via ds_read_b128 (2-way-free banks). A fragments from aggb global.
// After MFMA (barrier), wbuf is reused as f32 df[128][68] for the D scatter +
// coalesced BN/ELU/residual epilogue + next-layer logits.
template<bool LOGITS>
__global__ __launch_bounds__(512, 4) void k_gemmBM(const unsigned short* __restrict__ aggb,
    const unsigned short* __restrict__ Wfhi, const unsigned short* __restrict__ Wflo,
    const float* __restrict__ bias, const float* __restrict__ gma, const float* __restrict__ bta,
    const float* __restrict__ mea, const float* __restrict__ var,
    const float* __restrict__ hres, float* __restrict__ hout, unsigned short* __restrict__ hbf,
    const float* __restrict__ WaN, float* __restrict__ lg){
  __shared__ unsigned short wbuf[32768];   // 64KB: [0:16384)=Whi, [16384:32768)=Wlo; reused as df
  __shared__ float wal[512];
  int t = threadIdx.x, lane = t & 63, wv = t >> 6;
  int base = blockIdx.x * 128;
  if (LOGITS){ for (int i = t; i < 512; i += 512) wal[i] = WaN[i];
               if (t < 512) wal[t] = WaN[t]; }

  // stage W: 4096 uint4 total, 512 threads -> 8 iters (coalesced, L2-hot)
  {
    uint4* wb = (uint4*)wbuf;
    const uint4* gh = (const uint4*)Wfhi;
    const uint4* gl = (const uint4*)Wflo;
    #pragma unroll
    for (int i = 0; i < 4; i++) wb[t + i*512] = gh[t + i*512];
    #pragma unroll
    for (int i = 0; i < 4; i++) wb[2048 + t + i*512] = gl[t + i*512];
  }

  // A fragments from global (issued before the barrier to overlap staging)
  int anode = base + (wv << 4) + (lane & 15);
  if (anode >= NN) anode = NN - 1;
  const unsigned short* ap = aggb + (size_t)anode*256 + ((lane >> 4) << 3);
  bf16x8 af[8];
  #pragma unroll
  for (int s = 0; s < 8; s++) af[s] = *(const bf16x8*)(ap + s*32);

  __syncthreads();

  f32x4 acch[4], accl[4];
  #pragma unroll
  for (int c = 0; c < 4; c++){ acch[c] = (f32x4)0.f; accl[c] = (f32x4)0.f; }

  #pragma unroll
  for (int s = 0; s < 8; s++){
    #pragma unroll
    for (int c = 0; c < 4; c++){
      int fidx = ((c*8 + s)*64 + lane)*8;
      bf16x8 bh = *(const bf16x8*)(wbuf + fidx);
      bf16x8 bl = *(const bf16x8*)(wbuf + 16384 + fidx);
      acch[c] = __builtin_amdgcn_mfma_f32_16x16x32_bf16(af[s], bh, acch[c], 0, 0, 0);
      accl[c] = __builtin_amdgcn_mfma_f32_16x16x32_bf16(af[s], bl, accl[c], 0, 0, 0);
    }
  }
  __syncthreads();   // all W reads done; wbuf now reusable as df

  float* df = (float*)wbuf;   // [128][68] = 34816 B <= 65536 B
  {
    int rr = (wv << 4) + ((lane >> 4) << 2);
    int cc = lane & 15;
    #pragma unroll
    for (int c = 0; c < 4; c++)
      #pragma unroll
      for (int r = 0; r < 4; r++)
        df[(rr + r)*68 + (c << 4) + cc] = acch[c][r] + accl[c][r];
  }
  __syncthreads();

  // epilogue: bias + BN + ELU + residual (wave's own 16 nodes, j = lane)
  {
    int j = lane;
    float bi = bias[j], bt2 = bta[j], me = mea[j];
    float sc = rsqrtf(var[j] + 1e-5f) * gma[j];
    #pragma unroll 4
    for (int it = 0; it < 16; it++){
      int nd = (wv << 4) + it;
      int node = base + nd;
      if (node < NN){
        float o = df[nd*68 + j] + bi;
        o = (o - me)*sc + bt2;
        o = o > 0.f ? o : (__expf(o) - 1.f);
        o += hres[(size_t)node*64 + j];
        hout[(size_t)node*64 + j] = o;
        if (LOGITS){
          hbf[(size_t)node*64 + j] = f2b(o);
          df[nd*68 + j] = o;
        }
      }
    }
  }
  if (LOGITS){
    __syncthreads();
    int nd = t >> 2, jq = (t & 3) * 2;       // 512 threads -> 128 nodes x 2 j-pairs
    int node = base + nd;
    if (node < NN){
      float s0 = 0.f, s1 = 0.f;
      #pragma unroll 4
      for (int k = 0; k < 64; k += 4){
        float4 xv = *(const float4*)(df + nd*68 + k);
        const float* w0 = wal + k*8 + jq;
        s0 += xv.x*w0[0] + xv.y*w0[8] + xv.z*w0[16] + xv.w*w0[24];
        s1 += xv.x*w0[1] + xv.y*w0[9] + xv.z*w0[17] + xv.w*w0[25];
      }
      float2 sv = {s0, s1};
      *(float2*)(lg + (size_t)node*8 + jq) = sv;
    }
  }
}

// ---------------- pooling ----------------
__global__ __launch_bounds__(64) void k_pool(const float* __restrict__ h, const int* __restrict__ gstart,
                                             float* __restrict__ pooled){
  int g = blockIdx.x; int lane = threadIdx.x;
  int beg = gstart[g], end = gstart[g+1];
  float acc = 0.f;
  for (int n = beg; n < end; n++) acc += h[(size_t)n*64 + lane];
  float cnt = (float)(end - beg);
  pooled[(size_t)g*64 + lane] = acc / fmaxf(cnt, 1.f);
}

// ---------------- output MLP (wave per graph) ----------------
__global__ __launch_bounds__(256) void k_mlp(const float* __restrict__ pooled, const float* __restrict__ W1,
                                             const float* __restrict__ b1, const float* __restrict__ W2,
                                             const float* __restrict__ b2, float* __restrict__ out){
  int g = (blockIdx.x*256 + threadIdx.x) >> 6;
  int lane = threadIdx.x & 63;
  if (g >= GG) return;
  float pv = pooled[(size_t)g*64 + lane];
  int j = lane & 31, half = lane >> 5;
  float z = half ? 0.f : b1[j];
  #pragma unroll
  for (int c = 0; c < 32; c++){
    int cc = half*32 + c;
    z += __shfl(pv, cc) * W1[cc*32 + j];
  }
  z += __shfl_xor(z, 32);
  float o = 0.f;
  if (half == 0){
    z = z > 0.f ? z : (__expf(z) - 1.f);
    o = z * W2[j];
  }
  o += __shfl_xor(o, 1); o += __shfl_xor(o, 2); o += __shfl_xor(o, 4);
  o += __shfl_xor(o, 8); o += __shfl_xor(o, 16);
  if (lane == 0) out[g] = o + b2[0];
}

extern "C" void kernel_launch(void* const* d_in, const int* in_sizes, int n_in,
                              void* d_out, int out_size, void* d_ws, size_t ws_size,
                              hipStream_t stream) {
  const float* x    = (const float*)d_in[0];
  const int*   ei   = (const int*)d_in[1];
  const int*   batch= (const int*)d_in[2];
  const float* g0W  = (const float*)d_in[3];
  const float* g0as = (const float*)d_in[4];
  const float* g0ad = (const float*)d_in[5];
  const float* g0b  = (const float*)d_in[6];
  const float* bn0g = (const float*)d_in[7];
  const float* bn0b = (const float*)d_in[8];
  const float* bn0m = (const float*)d_in[9];
  const float* bn0v = (const float*)d_in[10];
  const float* gW   = (const float*)d_in[11];
  const float* gas  = (const float*)d_in[12];
  const float* gad  = (const float*)d_in[13];
  const float* gb   = (const float*)d_in[14];
  const float* bng  = (const float*)d_in[15];
  const float* bnb  = (const float*)d_in[16];
  const float* bnm  = (const float*)d_in[17];
  const float* bnv  = (const float*)d_in[18];
  const float* W1   = (const float*)d_in[19];
  const float* b1   = (const float*)d_in[20];
  const float* W2   = (const float*)d_in[21];
  const float* b2   = (const float*)d_in[22];
  float* out = (float*)d_out;
  (void)in_sizes; (void)n_in; (void)out_size; (void)ws_size;

  char* base = (char*)d_ws; size_t off = 0;
  auto alloc = [&](size_t b)->void*{ void* p = base + off; off = (off + b + 255) & ~(size_t)255; return p; };
  unsigned short* aggb = (unsigned short*)alloc((size_t)NN*256*2);  // 76.8 MB
  float* agg32  = (float*)alloc((size_t)NN*36*4);                   // 21.6 MB
  float* h_cur  = (float*)alloc((size_t)NN*64*4);                   // 38.4 MB
  unsigned short* hbf = (unsigned short*)alloc((size_t)NN*64*2);    // 19.2 MB
  float* lg     = (float*)alloc((size_t)NN*8*4);                    // 4.8 MB
  float* wE     = (float*)alloc((size_t)EE*4*4);                    // 9.6 MB
  float* wS     = (float*)alloc((size_t)NN*4*4);                    // 2.4 MB
  int*   deg    = (int*)alloc((size_t)NN*4);
  int*   fill   = (int*)alloc((size_t)NN*4);
  int*   rp     = (int*)alloc((size_t)(NN+1)*4);
  int*   col    = (int*)alloc((size_t)EE*4);
  int*   bsum   = (int*)alloc(1024*4);
  int*   gstart = (int*)alloc((size_t)(GG+1)*4);
  float* pooled = (float*)alloc((size_t)GG*64*4);
  float* Wa0    = (float*)alloc((size_t)72*4);
  float* Wa     = (float*)alloc((size_t)1536*4);
  float* Wstk0  = (float*)alloc((size_t)2304*4);
  unsigned short* Wfhi = (unsigned short*)alloc((size_t)3*16384*2);
  unsigned short* Wflo = (unsigned short*)alloc((size_t)3*16384*2);

  const int* esrc = ei;
  const int* edst = ei + EE;

  hipMemsetAsync(deg, 0, (size_t)NN*4, stream);
  hipMemsetAsync(fill, 0, (size_t)NN*4, stream);

  int nb1 = (NN + 255)/256;
  k_count<<<(EE+255)/256, 256, 0, stream>>>(edst, deg);
  k_scan1<<<nb1, 256, 0, stream>>>(deg, rp, bsum);
  k_scan2<<<1, 1024, 0, stream>>>(bsum, nb1);
  k_scan3<<<nb1, 256, 0, stream>>>(rp, bsum);
  k_fill<<<(EE+255)/256, 256, 0, stream>>>(esrc, edst, rp, fill, col);
  k_gstart<<<(GG+256)/256, 256, 0, stream>>>(batch, gstart);
  k_fold<<<16, 256, 0, stream>>>(g0W, g0as, g0ad, gW, gas, gad, Wa0, Wa, Wstk0);
  k_foldB<<<24, 256, 0, stream>>>(gW, Wfhi, Wflo);

  int nlog  = (NN*8 + 255)/256;   // 4688
  int nwave = NN/4;               // 37500 (wave per node)
  int n4b   = (NN + 15)/16;       // 9375  (4 nodes per wave, 16 per block)
  int ngB   = (NN + 63)/64;       // 2344
  int ngBM  = (NN + 127)/128;     // 1172
  int nnrm  = (NN*4 + 255)/256;   // 2344

  // layer 0 (layer-1 logits fused into gemmB36 via WaN = Wa[0])
  k_logits9<<<nlog, 256, 0, stream>>>(x, Wa0, lg);
  k_wgt<<<nnrm, 256, 0, stream>>>(lg, rp, col, wE, wS);
  k_agg9<<<nwave, 256, 0, stream>>>(x, wE, wS, rp, col, agg32);
  k_gemmB36<<<ngB, 256, 0, stream>>>(agg32, Wstk0, g0b, bn0g, bn0b, bn0m, bn0v,
                                     h_cur, hbf, Wa, lg);
  // layers 1..3 (split agg + MFMA with LDS-staged W)
  for (int i = 0; i < 3; i++){
    k_wgt<<<nnrm, 256, 0, stream>>>(lg, rp, col, wE, wS);
    k_agg4b<<<n4b, 256, 0, stream>>>(hbf, wE, wS, rp, col, aggb);
    if (i < 2)
      k_gemmBM<true><<<ngBM, 512, 0, stream>>>(aggb, Wfhi + (size_t)i*16384, Wflo + (size_t)i*16384,
                                               gb + (size_t)i*64,
                                               bng + (size_t)i*64, bnb + (size_t)i*64,
                                               bnm + (size_t)i*64, bnv + (size_t)i*64,
                                               h_cur, h_cur, hbf, Wa + (size_t)(i+1)*512, lg);
    else
      k_gemmBM<false><<<ngBM, 512, 0, stream>>>(aggb, Wfhi + (size_t)i*16384, Wflo + (size_t)i*16384,
                                                gb + (size_t)i*64,
                                                bng + (size_t)i*64, bnb + (size_t)i*64,
                                                bnm + (size_t)i*64, bnv + (size_t)i*64,
                                                h_cur, h_cur, hbf, nullptr, nullptr);
  }

  k_pool<<<GG, 64, 0, stream>>>(h_cur, gstart, pooled);
  k_mlp<<<(GG*64 + 255)/256, 256, 0, stream>>>(pooled, W1, b1, W2, b2, out);
}

// Round 15
// 499.140 us; speedup vs baseline: 1.1941x; 1.0304x over previous
//
#include <hip/hip_runtime.h>

#define NN 150000
#define EE 600000
#define HH 4
#define CC 64
#define GG 4096
#define INF 9

typedef __attribute__((ext_vector_type(8))) short bf16x8;
typedef __attribute__((ext_vector_type(4))) float f32x4;

__device__ __forceinline__ float lrelu(float a){ return a > 0.f ? a : 0.2f*a; }
__device__ __forceinline__ float b2f(unsigned short u){ return __uint_as_float((unsigned)u << 16); }
__device__ __forceinline__ unsigned short f2b(float f){
  unsigned u = __float_as_uint(f);
  return (unsigned short)((u + 0x7fff + ((u >> 16) & 1)) >> 16);   // RNE
}

// ---------------- CSR build ----------------
__global__ __launch_bounds__(256) void k_count(const int* __restrict__ dst, int* __restrict__ deg){
  int e = blockIdx.x*256 + threadIdx.x;
  if (e < EE) atomicAdd(&deg[dst[e]], 1);
}

__global__ __launch_bounds__(256) void k_scan1(const int* __restrict__ deg, int* __restrict__ excl, int* __restrict__ bsum){
  __shared__ int s[256];
  int tid = threadIdx.x, gid = blockIdx.x*256 + tid;
  int v = (gid < NN) ? deg[gid] : 0;
  s[tid] = v; __syncthreads();
  for (int off = 1; off < 256; off <<= 1){
    int t = (tid >= off) ? s[tid-off] : 0; __syncthreads();
    s[tid] += t; __syncthreads();
  }
  if (gid < NN) excl[gid] = s[tid] - v;
  if (tid == 255) bsum[blockIdx.x] = s[255];
}

__global__ __launch_bounds__(1024) void k_scan2(int* __restrict__ bsum, int nb){
  __shared__ int s[1024];
  int tid = threadIdx.x;
  int v = (tid < nb) ? bsum[tid] : 0;
  s[tid] = v; __syncthreads();
  for (int off = 1; off < 1024; off <<= 1){
    int t = (tid >= off) ? s[tid-off] : 0; __syncthreads();
    s[tid] += t; __syncthreads();
  }
  if (tid < nb) bsum[tid] = s[tid] - v;
}

__global__ __launch_bounds__(256) void k_scan3(int* __restrict__ rp, const int* __restrict__ bsum){
  int gid = blockIdx.x*256 + threadIdx.x;
  if (gid < NN) rp[gid] += bsum[blockIdx.x];
  if (gid == 0) rp[NN] = EE;
}

__global__ __launch_bounds__(256) void k_fill(const int* __restrict__ src, const int* __restrict__ dst,
                                              const int* __restrict__ rp, int* __restrict__ fill,
                                              int* __restrict__ col){
  int e = blockIdx.x*256 + threadIdx.x;
  if (e < EE){
    int d = dst[e];
    int pos = rp[d] + atomicAdd(&fill[d], 1);
    col[pos] = src[e];
  }
}

__global__ __launch_bounds__(256) void k_gstart(const int* __restrict__ batch, int* __restrict__ gstart){
  int g = blockIdx.x*256 + threadIdx.x;
  if (g > GG) return;
  int lo = 0, hi = NN;
  while (lo < hi){ int mid = (lo+hi) >> 1; if (batch[mid] < g) lo = mid+1; else hi = mid; }
  gstart[g] = lo;
}

// ---------------- fold weights (logits folds + layer-0 stack) ----------------
__global__ __launch_bounds__(256) void k_fold(const float* __restrict__ g0W, const float* __restrict__ g0as,
    const float* __restrict__ g0ad, const float* __restrict__ gW, const float* __restrict__ gas,
    const float* __restrict__ gad, float* __restrict__ Wa0, float* __restrict__ Wa,
    float* __restrict__ Wstk0){
  const int OFF1 = 72, OFF2 = OFF1 + 1536, OFF3 = OFF2 + 2304;
  int t = blockIdx.x*256 + threadIdx.x;
  if (t < OFF1){
    int k = t >> 3, j = t & 7, h = j & 3;
    const float* a = (j < 4) ? g0as : g0ad;
    float s = 0.f;
    for (int c = 0; c < 64; c++) s += g0W[k*256 + h*64 + c] * a[h*64 + c];
    Wa0[t] = s;
  } else if (t < OFF2){
    int u = t - OFF1;
    int i = u / 512, r = u % 512, k = r >> 3, j = r & 7, h = j & 3;
    const float* a = ((j < 4) ? gas : gad) + (size_t)i*256;
    float s = 0.f;
    for (int c = 0; c < 64; c++) s += gW[(size_t)i*16384 + k*256 + h*64 + c] * a[h*64 + c];
    Wa[u] = s;
  } else if (t < OFF3){
    int u = t - OFF2;           // u = k*64 + j, k = h*9+c
    int k = u >> 6, j = u & 63;
    int h = k / 9, c = k - h*9;
    Wstk0[u] = 0.25f * g0W[c*256 + h*64 + j];
  }
}

// ---------------- fold W into MFMA fragment order, split bf16 hi/lo ----------------
__global__ __launch_bounds__(256) void k_foldB(const float* __restrict__ gW,
    unsigned short* __restrict__ Wfhi, unsigned short* __restrict__ Wflo){
  int t = blockIdx.x*256 + threadIdx.x;
  if (t >= 3*4*8*64) return;
  int l = t & 63, s = (t >> 6) & 7, c = (t >> 9) & 3, i = t >> 11;
  size_t base = (size_t)i*16384 + (size_t)(((c*8 + s)*64 + l))*8;
  #pragma unroll
  for (int b = 0; b < 8; b++){
    int k = s*32 + ((l >> 4) << 3) + b;
    int h = k >> 6, ci = k & 63;
    int j = (c << 4) + (l & 15);
    float v = 0.25f * gW[(size_t)i*16384 + ci*256 + h*64 + j];
    unsigned short hi = f2b(v);
    unsigned short lo = f2b(v - b2f(hi));
    Wfhi[base + b] = hi;
    Wflo[base + b] = lo;
  }
}

// ---------------- logits (layer 0 only) ----------------
__global__ __launch_bounds__(256) void k_logits9(const float* __restrict__ hin, const float* __restrict__ Wa,
                                                 float* __restrict__ lg){
  int idx = blockIdx.x*256 + threadIdx.x;
  int node = idx >> 3, j = idx & 7;
  if (node >= NN) return;
  const float* r = hin + (size_t)node*INF;
  float s = 0.f;
  #pragma unroll
  for (int k = 0; k < INF; k++) s += r[k] * Wa[k*8 + j];
  lg[(size_t)node*8 + j] = s;
}

// ---------------- fused edge weights + normalization (thread per (node,head)) ----------------
__global__ __launch_bounds__(256) void k_wgt(const float* __restrict__ lg, const int* __restrict__ rp,
    const int* __restrict__ col, float* __restrict__ w, float* __restrict__ wself){
  int t = blockIdx.x*256 + threadIdx.x;
  if (t >= NN*4) return;
  int n = t >> 2, h = t & 3;
  float edv = lg[(size_t)n*8 + 4 + h];
  int rb = rp[n], re = rp[n+1];
  float s = 0.f;
  for (int p = rb; p < re; p++){
    float e = __expf(lrelu(lg[(size_t)col[p]*8 + h] + edv));
    w[(size_t)p*4 + h] = e;
    s += e;
  }
  float wsf = __expf(lrelu(lg[(size_t)n*8 + h] + edv));
  float inv = 1.f / (s + wsf);
  for (int p = rb; p < re; p++) w[(size_t)p*4 + h] *= inv;
  wself[t] = wsf * inv;
}

// ---------------- layer-0 aggregation: 4 nodes per wave (f32, 9 features) ----------------
// lane = (ns = lane>>4, q = lane&15); q < 9 active. col/w are 16-lane-uniform broadcasts;
// 4 independent edge streams per wave. Same accumulation order as before.
__global__ __launch_bounds__(256) void k_agg4f(const float* __restrict__ hin, const float* __restrict__ w,
     const float* __restrict__ wself, const int* __restrict__ rp, const int* __restrict__ col,
     float* __restrict__ aggo){
  int wv_id = (blockIdx.x*256 + threadIdx.x) >> 6;
  int lane = threadIdx.x & 63;
  int ns = lane >> 4, q = lane & 15;
  int node = wv_id*4 + ns;
  if (node >= NN) return;
  int rb = rp[node], re = rp[node+1];

  float4 ws4 = *(const float4*)(wself + (size_t)node*4);
  float xv = (q < INF) ? hin[(size_t)node*INF + q] : 0.f;
  float acc[4] = {ws4.x*xv, ws4.y*xv, ws4.z*xv, ws4.w*xv};

  int d = re - rb;
  d = max(d, __shfl_xor(d, 16));
  d = max(d, __shfl_xor(d, 32));

  for (int i = 0; i < d; i += 2){
    int e0 = rb + i, e1 = rb + i + 1;
    if (e0 < re){
      int s0 = col[e0];
      float4 w0 = *(const float4*)(w + (size_t)e0*4);
      float y = (q < INF) ? hin[(size_t)s0*INF + q] : 0.f;
      acc[0] += w0.x*y; acc[1] += w0.y*y; acc[2] += w0.z*y; acc[3] += w0.w*y;
    }
    if (e1 < re){
      int s1 = col[e1];
      float4 w1 = *(const float4*)(w + (size_t)e1*4);
      float y = (q < INF) ? hin[(size_t)s1*INF + q] : 0.f;
      acc[0] += w1.x*y; acc[1] += w1.y*y; acc[2] += w1.z*y; acc[3] += w1.w*y;
    }
  }

  if (q < INF){
    float* ap = aggo + (size_t)node*36 + q;
    ap[0] = acc[0]; ap[INF] = acc[1]; ap[2*INF] = acc[2]; ap[3*INF] = acc[3];
  }
}

// ---------------- layers 1-3 aggregation: 4 nodes per wave (bf16) ----------------
__global__ __launch_bounds__(256) void k_agg4b(const unsigned short* __restrict__ hb,
     const float* __restrict__ w, const float* __restrict__ wself, const int* __restrict__ rp,
     const int* __restrict__ col, unsigned short* __restrict__ aggb){
  int wv_id = (blockIdx.x*256 + threadIdx.x) >> 6;
  int lane = threadIdx.x & 63;
  int ns = lane >> 4, q = lane & 15;
  int node = wv_id*4 + ns;
  if (node >= NN) return;
  int rb = rp[node], re = rp[node+1];

  float4 ws4 = *(const float4*)(wself + (size_t)node*4);
  ushort4 xu = *(const ushort4*)(hb + (size_t)node*64 + q*4);
  float x0 = b2f(xu.x), x1 = b2f(xu.y), x2 = b2f(xu.z), x3 = b2f(xu.w);
  float acc[4][4];
  #pragma unroll
  for (int h = 0; h < 4; h++){
    float wh = (h==0)?ws4.x:(h==1)?ws4.y:(h==2)?ws4.z:ws4.w;
    acc[h][0] = wh*x0; acc[h][1] = wh*x1; acc[h][2] = wh*x2; acc[h][3] = wh*x3;
  }

  int d = re - rb;
  d = max(d, __shfl_xor(d, 16));
  d = max(d, __shfl_xor(d, 32));

  for (int i = 0; i < d; i += 2){
    int e0 = rb + i, e1 = rb + i + 1;
    bool v0 = e0 < re, v1 = e1 < re;
    if (v0){
      int s0 = col[e0];
      float4 w0 = *(const float4*)(w + (size_t)e0*4);
      ushort4 u0 = *(const ushort4*)(hb + (size_t)s0*64 + q*4);
      float y0 = b2f(u0.x), y1 = b2f(u0.y), y2 = b2f(u0.z), y3 = b2f(u0.w);
      acc[0][0] += w0.x*y0; acc[0][1] += w0.x*y1; acc[0][2] += w0.x*y2; acc[0][3] += w0.x*y3;
      acc[1][0] += w0.y*y0; acc[1][1] += w0.y*y1; acc[1][2] += w0.y*y2; acc[1][3] += w0.y*y3;
      acc[2][0] += w0.z*y0; acc[2][1] += w0.z*y1; acc[2][2] += w0.z*y2; acc[2][3] += w0.z*y3;
      acc[3][0] += w0.w*y0; acc[3][1] += w0.w*y1; acc[3][2] += w0.w*y2; acc[3][3] += w0.w*y3;
    }
    if (v1){
      int s1 = col[e1];
      float4 w1 = *(const float4*)(w + (size_t)e1*4);
      ushort4 u1 = *(const ushort4*)(hb + (size_t)s1*64 + q*4);
      float y0 = b2f(u1.x), y1 = b2f(u1.y), y2 = b2f(u1.z), y3 = b2f(u1.w);
      acc[0][0] += w1.x*y0; acc[0][1] += w1.x*y1; acc[0][2] += w1.x*y2; acc[0][3] += w1.x*y3;
      acc[1][0] += w1.y*y0; acc[1][1] += w1.y*y1; acc[1][2] += w1.y*y2; acc[1][3] += w1.y*y3;
      acc[2][0] += w1.z*y0; acc[2][1] += w1.z*y1; acc[2][2] += w1.z*y2; acc[2][3] += w1.z*y3;
      acc[3][0] += w1.w*y0; acc[3][1] += w1.w*y1; acc[3][2] += w1.w*y2; acc[3][3] += w1.w*y3;
    }
  }

  #pragma unroll
  for (int h = 0; h < 4; h++){
    ushort4 o = { f2b(acc[h][0]), f2b(acc[h][1]), f2b(acc[h][2]), f2b(acc[h][3]) };
    *(ushort4*)(aggb + (size_t)node*256 + h*64 + q*4) = o;
  }
}

// ---------------- layer-0 transform (f32, VALU) + epilogue + layer-1 logits ----------------
__global__ __launch_bounds__(256, 4) void k_gemmB36(const float* __restrict__ agg, const float* __restrict__ Ws,
    const float* __restrict__ bias, const float* __restrict__ gma, const float* __restrict__ bta,
    const float* __restrict__ mea, const float* __restrict__ var,
    float* __restrict__ hout, unsigned short* __restrict__ hbf,
    const float* __restrict__ WaN, float* __restrict__ lg){
  __shared__ float xs[64*68];
  __shared__ float ws[64*68];
  __shared__ float wal[512];
  int t = threadIdx.x;
  int base = blockIdx.x * 64;
  int r = t >> 4, c2 = t & 15;
  for (int i = t; i < 512; i += 256) wal[i] = WaN[i];

  for (int i = t; i < 64*9; i += 256){
    int nd = i / 9, kk = i - nd*9;
    float4 v = {0.f,0.f,0.f,0.f};
    if (base + nd < NN) v = *(const float4*)(agg + (size_t)(base+nd)*36 + kk*4);
    *(float4*)(xs + nd*44 + kk*4) = v;
  }
  for (int i = t; i < 36*16; i += 256){
    int k = i >> 4, c4 = i & 15;
    *(float4*)(ws + k*68 + c4*4) = *(const float4*)(Ws + (size_t)k*64 + c4*4);
  }
  __syncthreads();

  float acc[4][4];
  #pragma unroll
  for (int i = 0; i < 4; i++)
    #pragma unroll
    for (int u = 0; u < 4; u++) acc[i][u] = 0.f;

  #pragma unroll 2
  for (int k4 = 0; k4 < 36; k4 += 4){
    float4 xv[4], wv[4];
    #pragma unroll
    for (int i = 0; i < 4; i++) xv[i] = *(const float4*)(xs + (4*r+i)*44 + k4);
    #pragma unroll
    for (int u = 0; u < 4; u++) wv[u] = *(const float4*)(ws + (k4+u)*68 + 4*c2);
    #pragma unroll
    for (int i = 0; i < 4; i++){
      float xr[4] = {xv[i].x, xv[i].y, xv[i].z, xv[i].w};
      #pragma unroll
      for (int u = 0; u < 4; u++){
        acc[i][0] += xr[u]*wv[u].x; acc[i][1] += xr[u]*wv[u].y;
        acc[i][2] += xr[u]*wv[u].z; acc[i][3] += xr[u]*wv[u].w;
      }
    }
  }

  __syncthreads();
  int cb = 4*c2;
  float4 bi = *(const float4*)(bias + cb);
  float4 gm = *(const float4*)(gma + cb);
  float4 bt = *(const float4*)(bta + cb);
  float4 me = *(const float4*)(mea + cb);
  float4 va = *(const float4*)(var + cb);
  float sc0 = rsqrtf(va.x + 1e-5f)*gm.x, sc1 = rsqrtf(va.y + 1e-5f)*gm.y;
  float sc2 = rsqrtf(va.z + 1e-5f)*gm.z, sc3 = rsqrtf(va.w + 1e-5f)*gm.w;
  #pragma unroll
  for (int i = 0; i < 4; i++){
    int node = base + 4*r + i;
    if (node < NN){
      float o0 = (acc[i][0] + bi.x - me.x)*sc0 + bt.x;
      float o1 = (acc[i][1] + bi.y - me.y)*sc1 + bt.y;
      float o2 = (acc[i][2] + bi.z - me.z)*sc2 + bt.z;
      float o3 = (acc[i][3] + bi.w - me.w)*sc3 + bt.w;
      o0 = o0 > 0.f ? o0 : (__expf(o0) - 1.f);
      o1 = o1 > 0.f ? o1 : (__expf(o1) - 1.f);
      o2 = o2 > 0.f ? o2 : (__expf(o2) - 1.f);
      o3 = o3 > 0.f ? o3 : (__expf(o3) - 1.f);
      float4 st = {o0, o1, o2, o3};
      *(float4*)(hout + (size_t)node*64 + cb) = st;
      uint2 pb = { (unsigned)f2b(o0) | ((unsigned)f2b(o1) << 16),
                   (unsigned)f2b(o2) | ((unsigned)f2b(o3) << 16) };
      *(uint2*)(hbf + (size_t)node*64 + cb) = pb;
      *(float4*)(xs + (4*r+i)*68 + cb) = st;
    }
  }
  __syncthreads();
  int nd = t >> 2, jq = (t & 3) * 2;
  int node = base + nd;
  if (node < NN){
    float s0 = 0.f, s1 = 0.f;
    #pragma unroll 4
    for (int k = 0; k < 64; k += 4){
      float4 xv = *(const float4*)(xs + nd*68 + k);
      const float* w0 = wal + k*8 + jq;
      s0 += xv.x*w0[0] + xv.y*w0[8] + xv.z*w0[16] + xv.w*w0[24];
      s1 += xv.x*w0[1] + xv.y*w0[9] + xv.z*w0[17] + xv.w*w0[25];
    }
    float2 sv = {s0, s1};
    *(float2*)(lg + (size_t)node*8 + jq) = sv;
  }
}

// ---------------- layers 1-3 transform: MFMA with W staged in LDS ----------------
template<bool LOGITS>
__global__ __launch_bounds__(512, 4) void k_gemmBM(const unsigned short* __restrict__ aggb,
    const unsigned short* __restrict__ Wfhi, const unsigned short* __restrict__ Wflo,
    const float* __restrict__ bias, const float* __restrict__ gma, const float* __restrict__ bta,
    const float* __restrict__ mea, const float* __restrict__ var,
    const float* __restrict__ hres, float* __restrict__ hout, unsigned short* __restrict__ hbf,
    const float* __restrict__ WaN, float* __restrict__ lg){
  __shared__ unsigned short wbuf[32768];   // 64KB: [0:16384)=Whi, [16384:32768)=Wlo; reused as df
  __shared__ float wal[512];
  int t = threadIdx.x, lane = t & 63, wv = t >> 6;
  int base = blockIdx.x * 128;
  if (LOGITS){ wal[t] = WaN[t]; }

  // stage W: 4096 uint4 total, 512 threads (coalesced, L2-hot)
  {
    uint4* wb = (uint4*)wbuf;
    const uint4* gh = (const uint4*)Wfhi;
    const uint4* gl = (const uint4*)Wflo;
    #pragma unroll
    for (int i = 0; i < 4; i++) wb[t + i*512] = gh[t + i*512];
    #pragma unroll
    for (int i = 0; i < 4; i++) wb[2048 + t + i*512] = gl[t + i*512];
  }

  // A fragments from global (issued before the barrier to overlap staging)
  int anode = base + (wv << 4) + (lane & 15);
  if (anode >= NN) anode = NN - 1;
  const unsigned short* ap = aggb + (size_t)anode*256 + ((lane >> 4) << 3);
  bf16x8 af[8];
  #pragma unroll
  for (int s = 0; s < 8; s++) af[s] = *(const bf16x8*)(ap + s*32);

  __syncthreads();

  f32x4 acch[4], accl[4];
  #pragma unroll
  for (int c = 0; c < 4; c++){ acch[c] = (f32x4)0.f; accl[c] = (f32x4)0.f; }

  #pragma unroll
  for (int s = 0; s < 8; s++){
    #pragma unroll
    for (int c = 0; c < 4; c++){
      int fidx = ((c*8 + s)*64 + lane)*8;
      bf16x8 bh = *(const bf16x8*)(wbuf + fidx);
      bf16x8 bl = *(const bf16x8*)(wbuf + 16384 + fidx);
      acch[c] = __builtin_amdgcn_mfma_f32_16x16x32_bf16(af[s], bh, acch[c], 0, 0, 0);
      accl[c] = __builtin_amdgcn_mfma_f32_16x16x32_bf16(af[s], bl, accl[c], 0, 0, 0);
    }
  }
  __syncthreads();   // all W reads done; wbuf now reusable as df

  float* df = (float*)wbuf;   // [128][68] = 34816 B <= 65536 B
  {
    int rr = (wv << 4) + ((lane >> 4) << 2);
    int cc = lane & 15;
    #pragma unroll
    for (int c = 0; c < 4; c++)
      #pragma unroll
      for (int r = 0; r < 4; r++)
        df[(rr + r)*68 + (c << 4) + cc] = acch[c][r] + accl[c][r];
  }
  __syncthreads();

  // epilogue: bias + BN + ELU + residual (wave's own 16 nodes, j = lane)
  {
    int j = lane;
    float bi = bias[j], bt2 = bta[j], me = mea[j];
    float sc = rsqrtf(var[j] + 1e-5f) * gma[j];
    #pragma unroll 4
    for (int it = 0; it < 16; it++){
      int nd = (wv << 4) + it;
      int node = base + nd;
      if (node < NN){
        float o = df[nd*68 + j] + bi;
        o = (o - me)*sc + bt2;
        o = o > 0.f ? o : (__expf(o) - 1.f);
        o += hres[(size_t)node*64 + j];
        hout[(size_t)node*64 + j] = o;
        if (LOGITS){
          hbf[(size_t)node*64 + j] = f2b(o);
          df[nd*68 + j] = o;
        }
      }
    }
  }
  if (LOGITS){
    __syncthreads();
    int nd = t >> 2, jq = (t & 3) * 2;       // 512 threads -> 128 nodes x 2 j-pairs
    int node = base + nd;
    if (node < NN){
      float s0 = 0.f, s1 = 0.f;
      #pragma unroll 4
      for (int k = 0; k < 64; k += 4){
        float4 xv = *(const float4*)(df + nd*68 + k);
        const float* w0 = wal + k*8 + jq;
        s0 += xv.x*w0[0] + xv.y*w0[8] + xv.z*w0[16] + xv.w*w0[24];
        s1 += xv.x*w0[1] + xv.y*w0[9] + xv.z*w0[17] + xv.w*w0[25];
      }
      float2 sv = {s0, s1};
      *(float2*)(lg + (size_t)node*8 + jq) = sv;
    }
  }
}

// ---------------- pooling ----------------
__global__ __launch_bounds__(64) void k_pool(const float* __restrict__ h, const int* __restrict__ gstart,
                                             float* __restrict__ pooled){
  int g = blockIdx.x; int lane = threadIdx.x;
  int beg = gstart[g], end = gstart[g+1];
  float acc = 0.f;
  for (int n = beg; n < end; n++) acc += h[(size_t)n*64 + lane];
  float cnt = (float)(end - beg);
  pooled[(size_t)g*64 + lane] = acc / fmaxf(cnt, 1.f);
}

// ---------------- output MLP (wave per graph) ----------------
__global__ __launch_bounds__(256) void k_mlp(const float* __restrict__ pooled, const float* __restrict__ W1,
                                             const float* __restrict__ b1, const float* __restrict__ W2,
                                             const float* __restrict__ b2, float* __restrict__ out){
  int g = (blockIdx.x*256 + threadIdx.x) >> 6;
  int lane = threadIdx.x & 63;
  if (g >= GG) return;
  float pv = pooled[(size_t)g*64 + lane];
  int j = lane & 31, half = lane >> 5;
  float z = half ? 0.f : b1[j];
  #pragma unroll
  for (int c = 0; c < 32; c++){
    int cc = half*32 + c;
    z += __shfl(pv, cc) * W1[cc*32 + j];
  }
  z += __shfl_xor(z, 32);
  float o = 0.f;
  if (half == 0){
    z = z > 0.f ? z : (__expf(z) - 1.f);
    o = z * W2[j];
  }
  o += __shfl_xor(o, 1); o += __shfl_xor(o, 2); o += __shfl_xor(o, 4);
  o += __shfl_xor(o, 8); o += __shfl_xor(o, 16);
  if (lane == 0) out[g] = o + b2[0];
}

extern "C" void kernel_launch(void* const* d_in, const int* in_sizes, int n_in,
                              void* d_out, int out_size, void* d_ws, size_t ws_size,
                              hipStream_t stream) {
  const float* x    = (const float*)d_in[0];
  const int*   ei   = (const int*)d_in[1];
  const int*   batch= (const int*)d_in[2];
  const float* g0W  = (const float*)d_in[3];
  const float* g0as = (const float*)d_in[4];
  const float* g0ad = (const float*)d_in[5];
  const float* g0b  = (const float*)d_in[6];
  const float* bn0g = (const float*)d_in[7];
  const float* bn0b = (const float*)d_in[8];
  const float* bn0m = (const float*)d_in[9];
  const float* bn0v = (const float*)d_in[10];
  const float* gW   = (const float*)d_in[11];
  const float* gas  = (const float*)d_in[12];
  const float* gad  = (const float*)d_in[13];
  const float* gb   = (const float*)d_in[14];
  const float* bng  = (const float*)d_in[15];
  const float* bnb  = (const float*)d_in[16];
  const float* bnm  = (const float*)d_in[17];
  const float* bnv  = (const float*)d_in[18];
  const float* W1   = (const float*)d_in[19];
  const float* b1   = (const float*)d_in[20];
  const float* W2   = (const float*)d_in[21];
  const float* b2   = (const float*)d_in[22];
  float* out = (float*)d_out;
  (void)in_sizes; (void)n_in; (void)out_size; (void)ws_size;

  char* base = (char*)d_ws; size_t off = 0;
  auto alloc = [&](size_t b)->void*{ void* p = base + off; off = (off + b + 255) & ~(size_t)255; return p; };
  unsigned short* aggb = (unsigned short*)alloc((size_t)NN*256*2);  // 76.8 MB
  float* agg32  = (float*)alloc((size_t)NN*36*4);                   // 21.6 MB
  float* h_cur  = (float*)alloc((size_t)NN*64*4);                   // 38.4 MB
  unsigned short* hbf = (unsigned short*)alloc((size_t)NN*64*2);    // 19.2 MB
  float* lg     = (float*)alloc((size_t)NN*8*4);                    // 4.8 MB
  float* wE     = (float*)alloc((size_t)EE*4*4);                    // 9.6 MB
  float* wS     = (float*)alloc((size_t)NN*4*4);                    // 2.4 MB
  int*   deg    = (int*)alloc((size_t)NN*4);
  int*   fill   = (int*)alloc((size_t)NN*4);
  int*   rp     = (int*)alloc((size_t)(NN+1)*4);
  int*   col    = (int*)alloc((size_t)EE*4);
  int*   bsum   = (int*)alloc(1024*4);
  int*   gstart = (int*)alloc((size_t)(GG+1)*4);
  float* pooled = (float*)alloc((size_t)GG*64*4);
  float* Wa0    = (float*)alloc((size_t)72*4);
  float* Wa     = (float*)alloc((size_t)1536*4);
  float* Wstk0  = (float*)alloc((size_t)2304*4);
  unsigned short* Wfhi = (unsigned short*)alloc((size_t)3*16384*2);
  unsigned short* Wflo = (unsigned short*)alloc((size_t)3*16384*2);

  const int* esrc = ei;
  const int* edst = ei + EE;

  hipMemsetAsync(deg, 0, (size_t)NN*4, stream);
  hipMemsetAsync(fill, 0, (size_t)NN*4, stream);

  int nb1 = (NN + 255)/256;
  k_count<<<(EE+255)/256, 256, 0, stream>>>(edst, deg);
  k_scan1<<<nb1, 256, 0, stream>>>(deg, rp, bsum);
  k_scan2<<<1, 1024, 0, stream>>>(bsum, nb1);
  k_scan3<<<nb1, 256, 0, stream>>>(rp, bsum);
  k_fill<<<(EE+255)/256, 256, 0, stream>>>(esrc, edst, rp, fill, col);
  k_gstart<<<(GG+256)/256, 256, 0, stream>>>(batch, gstart);
  k_fold<<<16, 256, 0, stream>>>(g0W, g0as, g0ad, gW, gas, gad, Wa0, Wa, Wstk0);
  k_foldB<<<24, 256, 0, stream>>>(gW, Wfhi, Wflo);

  int nlog  = (NN*8 + 255)/256;   // 4688
  int n4b   = (NN + 15)/16;       // 9375  (4 nodes per wave, 16 per block)
  int ngB   = (NN + 63)/64;       // 2344
  int ngBM  = (NN + 127)/128;     // 1172
  int nnrm  = (NN*4 + 255)/256;   // 2344

  // layer 0 (layer-1 logits fused into gemmB36 via WaN = Wa[0])
  k_logits9<<<nlog, 256, 0, stream>>>(x, Wa0, lg);
  k_wgt<<<nnrm, 256, 0, stream>>>(lg, rp, col, wE, wS);
  k_agg4f<<<n4b, 256, 0, stream>>>(x, wE, wS, rp, col, agg32);
  k_gemmB36<<<ngB, 256, 0, stream>>>(agg32, Wstk0, g0b, bn0g, bn0b, bn0m, bn0v,
                                     h_cur, hbf, Wa, lg);
  // layers 1..3 (split agg + MFMA with LDS-staged W)
  for (int i = 0; i < 3; i++){
    k_wgt<<<nnrm, 256, 0, stream>>>(lg, rp, col, wE, wS);
    k_agg4b<<<n4b, 256, 0, stream>>>(hbf, wE, wS, rp, col, aggb);
    if (i < 2)
      k_gemmBM<true><<<ngBM, 512, 0, stream>>>(aggb, Wfhi + (size_t)i*16384, Wflo + (size_t)i*16384,
                                               gb + (size_t)i*64,
                                               bng + (size_t)i*64, bnb + (size_t)i*64,
                                               bnm + (size_t)i*64, bnv + (size_t)i*64,
                                               h_cur, h_cur, hbf, Wa + (size_t)(i+1)*512, lg);
    else
      k_gemmBM<false><<<ngBM, 512, 0, stream>>>(aggb, Wfhi + (size_t)i*16384, Wflo + (size_t)i*16384,
                                                gb + (size_t)i*64,
                                                bng + (size_t)i*64, bnb + (size_t)i*64,
                                                bnm + (size_t)i*64, bnv + (size_t)i*64,
                                                h_cur, h_cur, hbf, nullptr, nullptr);
  }

  k_pool<<<GG, 64, 0, stream>>>(h_cur, gstart, pooled);
  k_mlp<<<(GG*64 + 255)/256, 256, 0, stream>>>(pooled, W1, b1, W2, b2, out);
}

// Round 16
// 480.401 us; speedup vs baseline: 1.2406x; 1.0390x over previous
//
#include <hip/hip_runtime.h>

#define NN 150000
#define EE 600000
#define HH 4
#define CC 64
#define GG 4096
#define INF 9

typedef __attribute__((ext_vector_type(8))) short bf16x8;
typedef __attribute__((ext_vector_type(4))) float f32x4;

__device__ __forceinline__ float lrelu(float a){ return a > 0.f ? a : 0.2f*a; }
__device__ __forceinline__ float b2f(unsigned short u){ return __uint_as_float((unsigned)u << 16); }
__device__ __forceinline__ unsigned short f2b(float f){
  unsigned u = __float_as_uint(f);
  return (unsigned short)((u + 0x7fff + ((u >> 16) & 1)) >> 16);   // RNE
}

// ---------------- CSR build ----------------
__global__ __launch_bounds__(256) void k_count(const int* __restrict__ dst, int* __restrict__ deg){
  int e = blockIdx.x*256 + threadIdx.x;
  if (e < EE) atomicAdd(&deg[dst[e]], 1);
}

__global__ __launch_bounds__(256) void k_scan1(const int* __restrict__ deg, int* __restrict__ excl, int* __restrict__ bsum){
  __shared__ int s[256];
  int tid = threadIdx.x, gid = blockIdx.x*256 + tid;
  int v = (gid < NN) ? deg[gid] : 0;
  s[tid] = v; __syncthreads();
  for (int off = 1; off < 256; off <<= 1){
    int t = (tid >= off) ? s[tid-off] : 0; __syncthreads();
    s[tid] += t; __syncthreads();
  }
  if (gid < NN) excl[gid] = s[tid] - v;
  if (tid == 255) bsum[blockIdx.x] = s[255];
}

__global__ __launch_bounds__(1024) void k_scan2(int* __restrict__ bsum, int nb){
  __shared__ int s[1024];
  int tid = threadIdx.x;
  int v = (tid < nb) ? bsum[tid] : 0;
  s[tid] = v; __syncthreads();
  for (int off = 1; off < 1024; off <<= 1){
    int t = (tid >= off) ? s[tid-off] : 0; __syncthreads();
    s[tid] += t; __syncthreads();
  }
  if (tid < nb) bsum[tid] = s[tid] - v;
}

__global__ __launch_bounds__(256) void k_scan3(int* __restrict__ rp, const int* __restrict__ bsum){
  int gid = blockIdx.x*256 + threadIdx.x;
  if (gid < NN) rp[gid] += bsum[blockIdx.x];
  if (gid == 0) rp[NN] = EE;
}

__global__ __launch_bounds__(256) void k_fill(const int* __restrict__ src, const int* __restrict__ dst,
                                              const int* __restrict__ rp, int* __restrict__ fill,
                                              int* __restrict__ col){
  int e = blockIdx.x*256 + threadIdx.x;
  if (e < EE){
    int d = dst[e];
    int pos = rp[d] + atomicAdd(&fill[d], 1);
    col[pos] = src[e];
  }
}

__global__ __launch_bounds__(256) void k_gstart(const int* __restrict__ batch, int* __restrict__ gstart){
  int g = blockIdx.x*256 + threadIdx.x;
  if (g > GG) return;
  int lo = 0, hi = NN;
  while (lo < hi){ int mid = (lo+hi) >> 1; if (batch[mid] < g) lo = mid+1; else hi = mid; }
  gstart[g] = lo;
}

// ---------------- fold weights (logits folds + layer-0 stack) ----------------
__global__ __launch_bounds__(256) void k_fold(const float* __restrict__ g0W, const float* __restrict__ g0as,
    const float* __restrict__ g0ad, const float* __restrict__ gW, const float* __restrict__ gas,
    const float* __restrict__ gad, float* __restrict__ Wa0, float* __restrict__ Wa,
    float* __restrict__ Wstk0){
  const int OFF1 = 72, OFF2 = OFF1 + 1536, OFF3 = OFF2 + 2304;
  int t = blockIdx.x*256 + threadIdx.x;
  if (t < OFF1){
    int k = t >> 3, j = t & 7, h = j & 3;
    const float* a = (j < 4) ? g0as : g0ad;
    float s = 0.f;
    for (int c = 0; c < 64; c++) s += g0W[k*256 + h*64 + c] * a[h*64 + c];
    Wa0[t] = s;
  } else if (t < OFF2){
    int u = t - OFF1;
    int i = u / 512, r = u % 512, k = r >> 3, j = r & 7, h = j & 3;
    const float* a = ((j < 4) ? gas : gad) + (size_t)i*256;
    float s = 0.f;
    for (int c = 0; c < 64; c++) s += gW[(size_t)i*16384 + k*256 + h*64 + c] * a[h*64 + c];
    Wa[u] = s;
  } else if (t < OFF3){
    int u = t - OFF2;           // u = k*64 + j, k = h*9+c
    int k = u >> 6, j = u & 63;
    int h = k / 9, c = k - h*9;
    Wstk0[u] = 0.25f * g0W[c*256 + h*64 + j];
  }
}

// ---------------- fold W into MFMA fragment order, split bf16 hi/lo ----------------
__global__ __launch_bounds__(256) void k_foldB(const float* __restrict__ gW,
    unsigned short* __restrict__ Wfhi, unsigned short* __restrict__ Wflo){
  int t = blockIdx.x*256 + threadIdx.x;
  if (t >= 3*4*8*64) return;
  int l = t & 63, s = (t >> 6) & 7, c = (t >> 9) & 3, i = t >> 11;
  size_t base = (size_t)i*16384 + (size_t)(((c*8 + s)*64 + l))*8;
  #pragma unroll
  for (int b = 0; b < 8; b++){
    int k = s*32 + ((l >> 4) << 3) + b;
    int h = k >> 6, ci = k & 63;
    int j = (c << 4) + (l & 15);
    float v = 0.25f * gW[(size_t)i*16384 + ci*256 + h*64 + j];
    unsigned short hi = f2b(v);
    unsigned short lo = f2b(v - b2f(hi));
    Wfhi[base + b] = hi;
    Wflo[base + b] = lo;
  }
}

// ---------------- logits (layer 0 only) ----------------
__global__ __launch_bounds__(256) void k_logits9(const float* __restrict__ hin, const float* __restrict__ Wa,
                                                 float* __restrict__ lg){
  int idx = blockIdx.x*256 + threadIdx.x;
  int node = idx >> 3, j = idx & 7;
  if (node >= NN) return;
  const float* r = hin + (size_t)node*INF;
  float s = 0.f;
  #pragma unroll
  for (int k = 0; k < INF; k++) s += r[k] * Wa[k*8 + j];
  lg[(size_t)node*8 + j] = s;
}

// ---------------- edge weights (single-pass): unnormalized w + self weight + inverse ----------------
__global__ __launch_bounds__(256) void k_wgt(const float* __restrict__ lg, const int* __restrict__ rp,
    const int* __restrict__ col, float* __restrict__ w, float* __restrict__ wself,
    float* __restrict__ winv){
  int t = blockIdx.x*256 + threadIdx.x;
  if (t >= NN*4) return;
  int n = t >> 2, h = t & 3;
  float edv = lg[(size_t)n*8 + 4 + h];
  int rb = rp[n], re = rp[n+1];
  float s = 0.f;
  for (int p = rb; p < re; p++){
    float e = __expf(lrelu(lg[(size_t)col[p]*8 + h] + edv));
    w[(size_t)p*4 + h] = e;
    s += e;
  }
  float wsf = __expf(lrelu(lg[(size_t)n*8 + h] + edv));
  wself[t] = wsf;
  winv[t] = 1.f / (s + wsf);
}

// ---------------- layer-0 aggregation: 4 nodes per wave (f32, 9 features) ----------------
__global__ __launch_bounds__(256) void k_agg4f(const float* __restrict__ hin, const float* __restrict__ w,
     const float* __restrict__ wself, const float* __restrict__ winv,
     const int* __restrict__ rp, const int* __restrict__ col, float* __restrict__ aggo){
  int wv_id = (blockIdx.x*256 + threadIdx.x) >> 6;
  int lane = threadIdx.x & 63;
  int ns = lane >> 4, q = lane & 15;
  int node = wv_id*4 + ns;
  if (node >= NN) return;
  int rb = rp[node], re = rp[node+1];

  float4 ws4 = *(const float4*)(wself + (size_t)node*4);
  float4 wi4 = *(const float4*)(winv + (size_t)node*4);
  float xv = (q < INF) ? hin[(size_t)node*INF + q] : 0.f;
  float acc[4] = {ws4.x*xv, ws4.y*xv, ws4.z*xv, ws4.w*xv};

  int d = re - rb;
  d = max(d, __shfl_xor(d, 16));
  d = max(d, __shfl_xor(d, 32));

  for (int i = 0; i < d; i += 2){
    int e0 = rb + i, e1 = rb + i + 1;
    if (e0 < re){
      int s0 = col[e0];
      float4 w0 = *(const float4*)(w + (size_t)e0*4);
      float y = (q < INF) ? hin[(size_t)s0*INF + q] : 0.f;
      acc[0] += w0.x*y; acc[1] += w0.y*y; acc[2] += w0.z*y; acc[3] += w0.w*y;
    }
    if (e1 < re){
      int s1 = col[e1];
      float4 w1 = *(const float4*)(w + (size_t)e1*4);
      float y = (q < INF) ? hin[(size_t)s1*INF + q] : 0.f;
      acc[0] += w1.x*y; acc[1] += w1.y*y; acc[2] += w1.z*y; acc[3] += w1.w*y;
    }
  }

  if (q < INF){
    float* ap = aggo + (size_t)node*36 + q;
    ap[0] = acc[0]*wi4.x; ap[INF] = acc[1]*wi4.y;
    ap[2*INF] = acc[2]*wi4.z; ap[3*INF] = acc[3]*wi4.w;
  }
}

// ---------------- layers 1-3 aggregation: 4 nodes per wave (bf16) ----------------
__global__ __launch_bounds__(256) void k_agg4b(const unsigned short* __restrict__ hb,
     const float* __restrict__ w, const float* __restrict__ wself, const float* __restrict__ winv,
     const int* __restrict__ rp, const int* __restrict__ col, unsigned short* __restrict__ aggb){
  int wv_id = (blockIdx.x*256 + threadIdx.x) >> 6;
  int lane = threadIdx.x & 63;
  int ns = lane >> 4, q = lane & 15;
  int node = wv_id*4 + ns;
  if (node >= NN) return;
  int rb = rp[node], re = rp[node+1];

  float4 ws4 = *(const float4*)(wself + (size_t)node*4);
  float4 wi4 = *(const float4*)(winv + (size_t)node*4);
  ushort4 xu = *(const ushort4*)(hb + (size_t)node*64 + q*4);
  float x0 = b2f(xu.x), x1 = b2f(xu.y), x2 = b2f(xu.z), x3 = b2f(xu.w);
  float acc[4][4];
  #pragma unroll
  for (int h = 0; h < 4; h++){
    float wh = (h==0)?ws4.x:(h==1)?ws4.y:(h==2)?ws4.z:ws4.w;
    acc[h][0] = wh*x0; acc[h][1] = wh*x1; acc[h][2] = wh*x2; acc[h][3] = wh*x3;
  }

  int d = re - rb;
  d = max(d, __shfl_xor(d, 16));
  d = max(d, __shfl_xor(d, 32));

  for (int i = 0; i < d; i += 2){
    int e0 = rb + i, e1 = rb + i + 1;
    bool v0 = e0 < re, v1 = e1 < re;
    if (v0){
      int s0 = col[e0];
      float4 w0 = *(const float4*)(w + (size_t)e0*4);
      ushort4 u0 = *(const ushort4*)(hb + (size_t)s0*64 + q*4);
      float y0 = b2f(u0.x), y1 = b2f(u0.y), y2 = b2f(u0.z), y3 = b2f(u0.w);
      acc[0][0] += w0.x*y0; acc[0][1] += w0.x*y1; acc[0][2] += w0.x*y2; acc[0][3] += w0.x*y3;
      acc[1][0] += w0.y*y0; acc[1][1] += w0.y*y1; acc[1][2] += w0.y*y2; acc[1][3] += w0.y*y3;
      acc[2][0] += w0.z*y0; acc[2][1] += w0.z*y1; acc[2][2] += w0.z*y2; acc[2][3] += w0.z*y3;
      acc[3][0] += w0.w*y0; acc[3][1] += w0.w*y1; acc[3][2] += w0.w*y2; acc[3][3] += w0.w*y3;
    }
    if (v1){
      int s1 = col[e1];
      float4 w1 = *(const float4*)(w + (size_t)e1*4);
      ushort4 u1 = *(const ushort4*)(hb + (size_t)s1*64 + q*4);
      float y0 = b2f(u1.x), y1 = b2f(u1.y), y2 = b2f(u1.z), y3 = b2f(u1.w);
      acc[0][0] += w1.x*y0; acc[0][1] += w1.x*y1; acc[0][2] += w1.x*y2; acc[0][3] += w1.x*y3;
      acc[1][0] += w1.y*y0; acc[1][1] += w1.y*y1; acc[1][2] += w1.y*y2; acc[1][3] += w1.y*y3;
      acc[2][0] += w1.z*y0; acc[2][1] += w1.z*y1; acc[2][2] += w1.z*y2; acc[2][3] += w1.z*y3;
      acc[3][0] += w1.w*y0; acc[3][1] += w1.w*y1; acc[3][2] += w1.w*y2; acc[3][3] += w1.w*y3;
    }
  }

  #pragma unroll
  for (int h = 0; h < 4; h++){
    float wih = (h==0)?wi4.x:(h==1)?wi4.y:(h==2)?wi4.z:wi4.w;
    ushort4 o = { f2b(acc[h][0]*wih), f2b(acc[h][1]*wih), f2b(acc[h][2]*wih), f2b(acc[h][3]*wih) };
    *(ushort4*)(aggb + (size_t)node*256 + h*64 + q*4) = o;
  }
}

// ---------------- layer-0 transform (f32, VALU) + epilogue + layer-1 logits ----------------
__global__ __launch_bounds__(256, 4) void k_gemmB36(const float* __restrict__ agg, const float* __restrict__ Ws,
    const float* __restrict__ bias, const float* __restrict__ gma, const float* __restrict__ bta,
    const float* __restrict__ mea, const float* __restrict__ var,
    float* __restrict__ hout, unsigned short* __restrict__ hbf,
    const float* __restrict__ WaN, float* __restrict__ lg){
  __shared__ float xs[64*68];
  __shared__ float ws[64*68];
  __shared__ float wal[512];
  int t = threadIdx.x;
  int base = blockIdx.x * 64;
  int r = t >> 4, c2 = t & 15;
  for (int i = t; i < 512; i += 256) wal[i] = WaN[i];

  for (int i = t; i < 64*9; i += 256){
    int nd = i / 9, kk = i - nd*9;
    float4 v = {0.f,0.f,0.f,0.f};
    if (base + nd < NN) v = *(const float4*)(agg + (size_t)(base+nd)*36 + kk*4);
    *(float4*)(xs + nd*44 + kk*4) = v;
  }
  for (int i = t; i < 36*16; i += 256){
    int k = i >> 4, c4 = i & 15;
    *(float4*)(ws + k*68 + c4*4) = *(const float4*)(Ws + (size_t)k*64 + c4*4);
  }
  __syncthreads();

  float acc[4][4];
  #pragma unroll
  for (int i = 0; i < 4; i++)
    #pragma unroll
    for (int u = 0; u < 4; u++) acc[i][u] = 0.f;

  #pragma unroll 2
  for (int k4 = 0; k4 < 36; k4 += 4){
    float4 xv[4], wv[4];
    #pragma unroll
    for (int i = 0; i < 4; i++) xv[i] = *(const float4*)(xs + (4*r+i)*44 + k4);
    #pragma unroll
    for (int u = 0; u < 4; u++) wv[u] = *(const float4*)(ws + (k4+u)*68 + 4*c2);
    #pragma unroll
    for (int i = 0; i < 4; i++){
      float xr[4] = {xv[i].x, xv[i].y, xv[i].z, xv[i].w};
      #pragma unroll
      for (int u = 0; u < 4; u++){
        acc[i][0] += xr[u]*wv[u].x; acc[i][1] += xr[u]*wv[u].y;
        acc[i][2] += xr[u]*wv[u].z; acc[i][3] += xr[u]*wv[u].w;
      }
    }
  }

  __syncthreads();
  int cb = 4*c2;
  float4 bi = *(const float4*)(bias + cb);
  float4 gm = *(const float4*)(gma + cb);
  float4 bt = *(const float4*)(bta + cb);
  float4 me = *(const float4*)(mea + cb);
  float4 va = *(const float4*)(var + cb);
  float sc0 = rsqrtf(va.x + 1e-5f)*gm.x, sc1 = rsqrtf(va.y + 1e-5f)*gm.y;
  float sc2 = rsqrtf(va.z + 1e-5f)*gm.z, sc3 = rsqrtf(va.w + 1e-5f)*gm.w;
  #pragma unroll
  for (int i = 0; i < 4; i++){
    int node = base + 4*r + i;
    if (node < NN){
      float o0 = (acc[i][0] + bi.x - me.x)*sc0 + bt.x;
      float o1 = (acc[i][1] + bi.y - me.y)*sc1 + bt.y;
      float o2 = (acc[i][2] + bi.z - me.z)*sc2 + bt.z;
      float o3 = (acc[i][3] + bi.w - me.w)*sc3 + bt.w;
      o0 = o0 > 0.f ? o0 : (__expf(o0) - 1.f);
      o1 = o1 > 0.f ? o1 : (__expf(o1) - 1.f);
      o2 = o2 > 0.f ? o2 : (__expf(o2) - 1.f);
      o3 = o3 > 0.f ? o3 : (__expf(o3) - 1.f);
      float4 st = {o0, o1, o2, o3};
      *(float4*)(hout + (size_t)node*64 + cb) = st;
      uint2 pb = { (unsigned)f2b(o0) | ((unsigned)f2b(o1) << 16),
                   (unsigned)f2b(o2) | ((unsigned)f2b(o3) << 16) };
      *(uint2*)(hbf + (size_t)node*64 + cb) = pb;
      *(float4*)(xs + (4*r+i)*68 + cb) = st;
    }
  }
  __syncthreads();
  int nd = t >> 2, jq = (t & 3) * 2;
  int node = base + nd;
  if (node < NN){
    float s0 = 0.f, s1 = 0.f;
    #pragma unroll 4
    for (int k = 0; k < 64; k += 4){
      float4 xv = *(const float4*)(xs + nd*68 + k);
      const float* w0 = wal + k*8 + jq;
      s0 += xv.x*w0[0] + xv.y*w0[8] + xv.z*w0[16] + xv.w*w0[24];
      s1 += xv.x*w0[1] + xv.y*w0[9] + xv.z*w0[17] + xv.w*w0[25];
    }
    float2 sv = {s0, s1};
    *(float2*)(lg + (size_t)node*8 + jq) = sv;
  }
}

// ---------------- layers 1-3 transform: MFMA with W staged in LDS (192 nodes/block) ----------------
// 768 threads = 12 waves; wave wv -> nodes base+16wv..+15. W (64KB) staged once/block.
// After MFMA, wbuf reused as f32 df[192][68] (52.2KB) for scatter + epilogue + logits.
template<bool LOGITS>
__global__ __launch_bounds__(768, 6) void k_gemmBM(const unsigned short* __restrict__ aggb,
    const unsigned short* __restrict__ Wfhi, const unsigned short* __restrict__ Wflo,
    const float* __restrict__ bias, const float* __restrict__ gma, const float* __restrict__ bta,
    const float* __restrict__ mea, const float* __restrict__ var,
    const float* __restrict__ hres, float* __restrict__ hout, unsigned short* __restrict__ hbf,
    const float* __restrict__ WaN, float* __restrict__ lg){
  __shared__ unsigned short wbuf[32768];   // 64KB: Whi | Wlo; reused as df[192][68] f32
  __shared__ float wal[512];
  int t = threadIdx.x, lane = t & 63, wv = t >> 6;
  int base = blockIdx.x * 192;
  if (LOGITS && t < 512) wal[t] = WaN[t];

  // stage W: 2048+2048 uint4, 768 threads
  {
    uint4* wb = (uint4*)wbuf;
    const uint4* gh = (const uint4*)Wfhi;
    const uint4* gl = (const uint4*)Wflo;
    for (int i = t; i < 2048; i += 768) wb[i] = gh[i];
    for (int i = t; i < 2048; i += 768) wb[2048 + i] = gl[i];
  }

  // A fragments from global (issued before the barrier to overlap staging)
  int anode = base + (wv << 4) + (lane & 15);
  if (anode >= NN) anode = NN - 1;
  const unsigned short* ap = aggb + (size_t)anode*256 + ((lane >> 4) << 3);
  bf16x8 af[8];
  #pragma unroll
  for (int s = 0; s < 8; s++) af[s] = *(const bf16x8*)(ap + s*32);

  __syncthreads();

  f32x4 acch[4], accl[4];
  #pragma unroll
  for (int c = 0; c < 4; c++){ acch[c] = (f32x4)0.f; accl[c] = (f32x4)0.f; }

  #pragma unroll
  for (int s = 0; s < 8; s++){
    #pragma unroll
    for (int c = 0; c < 4; c++){
      int fidx = ((c*8 + s)*64 + lane)*8;
      bf16x8 bh = *(const bf16x8*)(wbuf + fidx);
      bf16x8 bl = *(const bf16x8*)(wbuf + 16384 + fidx);
      acch[c] = __builtin_amdgcn_mfma_f32_16x16x32_bf16(af[s], bh, acch[c], 0, 0, 0);
      accl[c] = __builtin_amdgcn_mfma_f32_16x16x32_bf16(af[s], bl, accl[c], 0, 0, 0);
    }
  }
  __syncthreads();   // all W reads done; wbuf now reusable as df

  float* df = (float*)wbuf;   // [192][68] = 52224 B <= 65536 B
  {
    int rr = (wv << 4) + ((lane >> 4) << 2);
    int cc = lane & 15;
    #pragma unroll
    for (int c = 0; c < 4; c++)
      #pragma unroll
      for (int r = 0; r < 4; r++)
        df[(rr + r)*68 + (c << 4) + cc] = acch[c][r] + accl[c][r];
  }
  __syncthreads();

  // epilogue: bias + BN + ELU + residual (wave's own 16 nodes, j = lane)
  {
    int j = lane;
    float bi = bias[j], bt2 = bta[j], me = mea[j];
    float sc = rsqrtf(var[j] + 1e-5f) * gma[j];
    #pragma unroll 4
    for (int it = 0; it < 16; it++){
      int nd = (wv << 4) + it;
      int node = base + nd;
      if (node < NN){
        float o = df[nd*68 + j] + bi;
        o = (o - me)*sc + bt2;
        o = o > 0.f ? o : (__expf(o) - 1.f);
        o += hres[(size_t)node*64 + j];
        hout[(size_t)node*64 + j] = o;
        if (LOGITS){
          hbf[(size_t)node*64 + j] = f2b(o);
          df[nd*68 + j] = o;
        }
      }
    }
  }
  if (LOGITS){
    __syncthreads();
    int nd = t >> 2, jq = (t & 3) * 2;       // 768 threads -> 192 nodes x 2 j-pairs
    int node = base + nd;
    if (node < NN){
      float s0 = 0.f, s1 = 0.f;
      #pragma unroll 4
      for (int k = 0; k < 64; k += 4){
        float4 xv = *(const float4*)(df + nd*68 + k);
        const float* w0 = wal + k*8 + jq;
        s0 += xv.x*w0[0] + xv.y*w0[8] + xv.z*w0[16] + xv.w*w0[24];
        s1 += xv.x*w0[1] + xv.y*w0[9] + xv.z*w0[17] + xv.w*w0[25];
      }
      float2 sv = {s0, s1};
      *(float2*)(lg + (size_t)node*8 + jq) = sv;
    }
  }
}

// ---------------- pooling ----------------
__global__ __launch_bounds__(64) void k_pool(const float* __restrict__ h, const int* __restrict__ gstart,
                                             float* __restrict__ pooled){
  int g = blockIdx.x; int lane = threadIdx.x;
  int beg = gstart[g], end = gstart[g+1];
  float acc = 0.f;
  for (int n = beg; n < end; n++) acc += h[(size_t)n*64 + lane];
  float cnt = (float)(end - beg);
  pooled[(size_t)g*64 + lane] = acc / fmaxf(cnt, 1.f);
}

// ---------------- output MLP (wave per graph) ----------------
__global__ __launch_bounds__(256) void k_mlp(const float* __restrict__ pooled, const float* __restrict__ W1,
                                             const float* __restrict__ b1, const float* __restrict__ W2,
                                             const float* __restrict__ b2, float* __restrict__ out){
  int g = (blockIdx.x*256 + threadIdx.x) >> 6;
  int lane = threadIdx.x & 63;
  if (g >= GG) return;
  float pv = pooled[(size_t)g*64 + lane];
  int j = lane & 31, half = lane >> 5;
  float z = half ? 0.f : b1[j];
  #pragma unroll
  for (int c = 0; c < 32; c++){
    int cc = half*32 + c;
    z += __shfl(pv, cc) * W1[cc*32 + j];
  }
  z += __shfl_xor(z, 32);
  float o = 0.f;
  if (half == 0){
    z = z > 0.f ? z : (__expf(z) - 1.f);
    o = z * W2[j];
  }
  o += __shfl_xor(o, 1); o += __shfl_xor(o, 2); o += __shfl_xor(o, 4);
  o += __shfl_xor(o, 8); o += __shfl_xor(o, 16);
  if (lane == 0) out[g] = o + b2[0];
}

extern "C" void kernel_launch(void* const* d_in, const int* in_sizes, int n_in,
                              void* d_out, int out_size, void* d_ws, size_t ws_size,
                              hipStream_t stream) {
  const float* x    = (const float*)d_in[0];
  const int*   ei   = (const int*)d_in[1];
  const int*   batch= (const int*)d_in[2];
  const float* g0W  = (const float*)d_in[3];
  const float* g0as = (const float*)d_in[4];
  const float* g0ad = (const float*)d_in[5];
  const float* g0b  = (const float*)d_in[6];
  const float* bn0g = (const float*)d_in[7];
  const float* bn0b = (const float*)d_in[8];
  const float* bn0m = (const float*)d_in[9];
  const float* bn0v = (const float*)d_in[10];
  const float* gW   = (const float*)d_in[11];
  const float* gas  = (const float*)d_in[12];
  const float* gad  = (const float*)d_in[13];
  const float* gb   = (const float*)d_in[14];
  const float* bng  = (const float*)d_in[15];
  const float* bnb  = (const float*)d_in[16];
  const float* bnm  = (const float*)d_in[17];
  const float* bnv  = (const float*)d_in[18];
  const float* W1   = (const float*)d_in[19];
  const float* b1   = (const float*)d_in[20];
  const float* W2   = (const float*)d_in[21];
  const float* b2   = (const float*)d_in[22];
  float* out = (float*)d_out;
  (void)in_sizes; (void)n_in; (void)out_size; (void)ws_size;

  char* base = (char*)d_ws; size_t off = 0;
  auto alloc = [&](size_t b)->void*{ void* p = base + off; off = (off + b + 255) & ~(size_t)255; return p; };
  unsigned short* aggb = (unsigned short*)alloc((size_t)NN*256*2);  // 76.8 MB
  float* agg32  = (float*)alloc((size_t)NN*36*4);                   // 21.6 MB
  float* h_cur  = (float*)alloc((size_t)NN*64*4);                   // 38.4 MB
  unsigned short* hbf = (unsigned short*)alloc((size_t)NN*64*2);    // 19.2 MB
  float* lg     = (float*)alloc((size_t)NN*8*4);                    // 4.8 MB
  float* wE     = (float*)alloc((size_t)EE*4*4);                    // 9.6 MB
  float* wS     = (float*)alloc((size_t)NN*4*4);                    // 2.4 MB
  float* wI     = (float*)alloc((size_t)NN*4*4);                    // 2.4 MB
  int*   deg    = (int*)alloc((size_t)NN*4);
  int*   fill   = (int*)alloc((size_t)NN*4);
  int*   rp     = (int*)alloc((size_t)(NN+1)*4);
  int*   col    = (int*)alloc((size_t)EE*4);
  int*   bsum   = (int*)alloc(1024*4);
  int*   gstart = (int*)alloc((size_t)(GG+1)*4);
  float* pooled = (float*)alloc((size_t)GG*64*4);
  float* Wa0    = (float*)alloc((size_t)72*4);
  float* Wa     = (float*)alloc((size_t)1536*4);
  float* Wstk0  = (float*)alloc((size_t)2304*4);
  unsigned short* Wfhi = (unsigned short*)alloc((size_t)3*16384*2);
  unsigned short* Wflo = (unsigned short*)alloc((size_t)3*16384*2);

  const int* esrc = ei;
  const int* edst = ei + EE;

  hipMemsetAsync(deg, 0, (size_t)NN*4, stream);
  hipMemsetAsync(fill, 0, (size_t)NN*4, stream);

  int nb1 = (NN + 255)/256;
  k_count<<<(EE+255)/256, 256, 0, stream>>>(edst, deg);
  k_scan1<<<nb1, 256, 0, stream>>>(deg, rp, bsum);
  k_scan2<<<1, 1024, 0, stream>>>(bsum, nb1);
  k_scan3<<<nb1, 256, 0, stream>>>(rp, bsum);
  k_fill<<<(EE+255)/256, 256, 0, stream>>>(esrc, edst, rp, fill, col);
  k_gstart<<<(GG+256)/256, 256, 0, stream>>>(batch, gstart);
  k_fold<<<16, 256, 0, stream>>>(g0W, g0as, g0ad, gW, gas, gad, Wa0, Wa, Wstk0);
  k_foldB<<<24, 256, 0, stream>>>(gW, Wfhi, Wflo);

  int nlog  = (NN*8 + 255)/256;   // 4688
  int n4b   = (NN + 15)/16;       // 9375  (4 nodes per wave, 16 per block)
  int ngB   = (NN + 63)/64;       // 2344
  int ngBM  = (NN + 191)/192;     // 782
  int nnrm  = (NN*4 + 255)/256;   // 2344

  // layer 0 (layer-1 logits fused into gemmB36 via WaN = Wa[0])
  k_logits9<<<nlog, 256, 0, stream>>>(x, Wa0, lg);
  k_wgt<<<nnrm, 256, 0, stream>>>(lg, rp, col, wE, wS, wI);
  k_agg4f<<<n4b, 256, 0, stream>>>(x, wE, wS, wI, rp, col, agg32);
  k_gemmB36<<<ngB, 256, 0, stream>>>(agg32, Wstk0, g0b, bn0g, bn0b, bn0m, bn0v,
                                     h_cur, hbf, Wa, lg);
  // layers 1..3 (split agg + MFMA with LDS-staged W)
  for (int i = 0; i < 3; i++){
    k_wgt<<<nnrm, 256, 0, stream>>>(lg, rp, col, wE, wS, wI);
    k_agg4b<<<n4b, 256, 0, stream>>>(hbf, wE, wS, wI, rp, col, aggb);
    if (i < 2)
      k_gemmBM<true><<<ngBM, 768, 0, stream>>>(aggb, Wfhi + (size_t)i*16384, Wflo + (size_t)i*16384,
                                               gb + (size_t)i*64,
                                               bng + (size_t)i*64, bnb + (size_t)i*64,
                                               bnm + (size_t)i*64, bnv + (size_t)i*64,
                                               h_cur, h_cur, hbf, Wa + (size_t)(i+1)*512, lg);
    else
      k_gemmBM<false><<<ngBM, 768, 0, stream>>>(aggb, Wfhi + (size_t)i*16384, Wflo + (size_t)i*16384,
                                                gb + (size_t)i*64,
                                                bng + (size_t)i*64, bnb + (size_t)i*64,
                                                bnm + (size_t)i*64, bnv + (size_t)i*64,
                                                h_cur, h_cur, hbf, nullptr, nullptr);
  }

  k_pool<<<GG, 64, 0, stream>>>(h_cur, gstart, pooled);
  k_mlp<<<(GG*64 + 255)/256, 256, 0, stream>>>(pooled, W1, b1, W2, b2, out);
}

// Round 17
// 469.920 us; speedup vs baseline: 1.2683x; 1.0223x over previous
//
#include <hip/hip_runtime.h>

#define NN 150000
#define EE 600000
#define HH 4
#define CC 64
#define GG 4096
#define INF 9

typedef __attribute__((ext_vector_type(8))) short bf16x8;
typedef __attribute__((ext_vector_type(4))) float f32x4;

__device__ __forceinline__ float lrelu(float a){ return a > 0.f ? a : 0.2f*a; }
__device__ __forceinline__ float b2f(unsigned short u){ return __uint_as_float((unsigned)u << 16); }
__device__ __forceinline__ unsigned short f2b(float f){
  unsigned u = __float_as_uint(f);
  return (unsigned short)((u + 0x7fff + ((u >> 16) & 1)) >> 16);   // RNE
}

// ---------------- CSR build ----------------
__global__ __launch_bounds__(256) void k_count(const int* __restrict__ dst, int* __restrict__ deg){
  int e = blockIdx.x*256 + threadIdx.x;
  if (e < EE) atomicAdd(&deg[dst[e]], 1);
}

__global__ __launch_bounds__(256) void k_scan1(const int* __restrict__ deg, int* __restrict__ excl, int* __restrict__ bsum){
  __shared__ int s[256];
  int tid = threadIdx.x, gid = blockIdx.x*256 + tid;
  int v = (gid < NN) ? deg[gid] : 0;
  s[tid] = v; __syncthreads();
  for (int off = 1; off < 256; off <<= 1){
    int t = (tid >= off) ? s[tid-off] : 0; __syncthreads();
    s[tid] += t; __syncthreads();
  }
  if (gid < NN) excl[gid] = s[tid] - v;
  if (tid == 255) bsum[blockIdx.x] = s[255];
}

__global__ __launch_bounds__(1024) void k_scan2(int* __restrict__ bsum, int nb){
  __shared__ int s[1024];
  int tid = threadIdx.x;
  int v = (tid < nb) ? bsum[tid] : 0;
  s[tid] = v; __syncthreads();
  for (int off = 1; off < 1024; off <<= 1){
    int t = (tid >= off) ? s[tid-off] : 0; __syncthreads();
    s[tid] += t; __syncthreads();
  }
  if (tid < nb) bsum[tid] = s[tid] - v;
}

__global__ __launch_bounds__(256) void k_scan3(int* __restrict__ rp, const int* __restrict__ bsum){
  int gid = blockIdx.x*256 + threadIdx.x;
  if (gid < NN) rp[gid] += bsum[blockIdx.x];
  if (gid == 0) rp[NN] = EE;
}

__global__ __launch_bounds__(256) void k_fill(const int* __restrict__ src, const int* __restrict__ dst,
                                              const int* __restrict__ rp, int* __restrict__ fill,
                                              int* __restrict__ col){
  int e = blockIdx.x*256 + threadIdx.x;
  if (e < EE){
    int d = dst[e];
    int pos = rp[d] + atomicAdd(&fill[d], 1);
    col[pos] = src[e];
  }
}

__global__ __launch_bounds__(256) void k_gstart(const int* __restrict__ batch, int* __restrict__ gstart){
  int g = blockIdx.x*256 + threadIdx.x;
  if (g > GG) return;
  int lo = 0, hi = NN;
  while (lo < hi){ int mid = (lo+hi) >> 1; if (batch[mid] < g) lo = mid+1; else hi = mid; }
  gstart[g] = lo;
}

// ---------------- fold weights (logits folds + layer-0 stack) ----------------
__global__ __launch_bounds__(256) void k_fold(const float* __restrict__ g0W, const float* __restrict__ g0as,
    const float* __restrict__ g0ad, const float* __restrict__ gW, const float* __restrict__ gas,
    const float* __restrict__ gad, float* __restrict__ Wa0, float* __restrict__ Wa,
    float* __restrict__ Wstk0){
  const int OFF1 = 72, OFF2 = OFF1 + 1536, OFF3 = OFF2 + 2304;
  int t = blockIdx.x*256 + threadIdx.x;
  if (t < OFF1){
    int k = t >> 3, j = t & 7, h = j & 3;
    const float* a = (j < 4) ? g0as : g0ad;
    float s = 0.f;
    for (int c = 0; c < 64; c++) s += g0W[k*256 + h*64 + c] * a[h*64 + c];
    Wa0[t] = s;
  } else if (t < OFF2){
    int u = t - OFF1;
    int i = u / 512, r = u % 512, k = r >> 3, j = r & 7, h = j & 3;
    const float* a = ((j < 4) ? gas : gad) + (size_t)i*256;
    float s = 0.f;
    for (int c = 0; c < 64; c++) s += gW[(size_t)i*16384 + k*256 + h*64 + c] * a[h*64 + c];
    Wa[u] = s;
  } else if (t < OFF3){
    int u = t - OFF2;           // u = k*64 + j, k = h*9+c
    int k = u >> 6, j = u & 63;
    int h = k / 9, c = k - h*9;
    Wstk0[u] = 0.25f * g0W[c*256 + h*64 + j];
  }
}

// ---------------- fold W into MFMA fragment order, split bf16 hi/lo ----------------
__global__ __launch_bounds__(256) void k_foldB(const float* __restrict__ gW,
    unsigned short* __restrict__ Wfhi, unsigned short* __restrict__ Wflo){
  int t = blockIdx.x*256 + threadIdx.x;
  if (t >= 3*4*8*64) return;
  int l = t & 63, s = (t >> 6) & 7, c = (t >> 9) & 3, i = t >> 11;
  size_t base = (size_t)i*16384 + (size_t)(((c*8 + s)*64 + l))*8;
  #pragma unroll
  for (int b = 0; b < 8; b++){
    int k = s*32 + ((l >> 4) << 3) + b;
    int h = k >> 6, ci = k & 63;
    int j = (c << 4) + (l & 15);
    float v = 0.25f * gW[(size_t)i*16384 + ci*256 + h*64 + j];
    unsigned short hi = f2b(v);
    unsigned short lo = f2b(v - b2f(hi));
    Wfhi[base + b] = hi;
    Wflo[base + b] = lo;
  }
}

// ---------------- logits (layer 0 only) ----------------
__global__ __launch_bounds__(256) void k_logits9(const float* __restrict__ hin, const float* __restrict__ Wa,
                                                 float* __restrict__ lg){
  int idx = blockIdx.x*256 + threadIdx.x;
  int node = idx >> 3, j = idx & 7;
  if (node >= NN) return;
  const float* r = hin + (size_t)node*INF;
  float s = 0.f;
  #pragma unroll
  for (int k = 0; k < INF; k++) s += r[k] * Wa[k*8 + j];
  lg[(size_t)node*8 + j] = s;
}

// ---------------- edge weights (single-pass): unnormalized w + self weight + inverse ----------------
__global__ __launch_bounds__(256) void k_wgt(const float* __restrict__ lg, const int* __restrict__ rp,
    const int* __restrict__ col, float* __restrict__ w, float* __restrict__ wself,
    float* __restrict__ winv){
  int t = blockIdx.x*256 + threadIdx.x;
  if (t >= NN*4) return;
  int n = t >> 2, h = t & 3;
  float edv = lg[(size_t)n*8 + 4 + h];
  int rb = rp[n], re = rp[n+1];
  float s = 0.f;
  for (int p = rb; p < re; p++){
    float e = __expf(lrelu(lg[(size_t)col[p]*8 + h] + edv));
    w[(size_t)p*4 + h] = e;
    s += e;
  }
  float wsf = __expf(lrelu(lg[(size_t)n*8 + h] + edv));
  wself[t] = wsf;
  winv[t] = 1.f / (s + wsf);
}

// ---------------- layer-0 aggregation: 4 nodes per wave (f32, 9 features), 4-edge unroll ----------------
__global__ __launch_bounds__(256) void k_agg4f(const float* __restrict__ hin, const float* __restrict__ w,
     const float* __restrict__ wself, const float* __restrict__ winv,
     const int* __restrict__ rp, const int* __restrict__ col, float* __restrict__ aggo){
  int wv_id = (blockIdx.x*256 + threadIdx.x) >> 6;
  int lane = threadIdx.x & 63;
  int ns = lane >> 4, q = lane & 15;
  int node = wv_id*4 + ns;
  if (node >= NN) return;
  int rb = rp[node], re = rp[node+1];

  float4 ws4 = *(const float4*)(wself + (size_t)node*4);
  float4 wi4 = *(const float4*)(winv + (size_t)node*4);
  float xv = (q < INF) ? hin[(size_t)node*INF + q] : 0.f;
  float acc[4] = {ws4.x*xv, ws4.y*xv, ws4.z*xv, ws4.w*xv};

  int d = re - rb;
  d = max(d, __shfl_xor(d, 16));
  d = max(d, __shfl_xor(d, 32));

  for (int i = 0; i < d; i += 4){
    #pragma unroll
    for (int u = 0; u < 4; u++){
      int e = rb + i + u;
      if (e < re){
        int s0 = col[e];
        float4 w0 = *(const float4*)(w + (size_t)e*4);
        float y = (q < INF) ? hin[(size_t)s0*INF + q] : 0.f;
        acc[0] += w0.x*y; acc[1] += w0.y*y; acc[2] += w0.z*y; acc[3] += w0.w*y;
      }
    }
  }

  if (q < INF){
    float* ap = aggo + (size_t)node*36 + q;
    ap[0] = acc[0]*wi4.x; ap[INF] = acc[1]*wi4.y;
    ap[2*INF] = acc[2]*wi4.z; ap[3*INF] = acc[3]*wi4.w;
  }
}

// ---------------- layers 1-3 aggregation: 4 nodes per wave (bf16), 4-edge unroll ----------------
__global__ __launch_bounds__(256) void k_agg4b(const unsigned short* __restrict__ hb,
     const float* __restrict__ w, const float* __restrict__ wself, const float* __restrict__ winv,
     const int* __restrict__ rp, const int* __restrict__ col, unsigned short* __restrict__ aggb){
  int wv_id = (blockIdx.x*256 + threadIdx.x) >> 6;
  int lane = threadIdx.x & 63;
  int ns = lane >> 4, q = lane & 15;
  int node = wv_id*4 + ns;
  if (node >= NN) return;
  int rb = rp[node], re = rp[node+1];

  float4 ws4 = *(const float4*)(wself + (size_t)node*4);
  float4 wi4 = *(const float4*)(winv + (size_t)node*4);
  ushort4 xu = *(const ushort4*)(hb + (size_t)node*64 + q*4);
  float x0 = b2f(xu.x), x1 = b2f(xu.y), x2 = b2f(xu.z), x3 = b2f(xu.w);
  float acc[4][4];
  #pragma unroll
  for (int h = 0; h < 4; h++){
    float wh = (h==0)?ws4.x:(h==1)?ws4.y:(h==2)?ws4.z:ws4.w;
    acc[h][0] = wh*x0; acc[h][1] = wh*x1; acc[h][2] = wh*x2; acc[h][3] = wh*x3;
  }

  int d = re - rb;
  d = max(d, __shfl_xor(d, 16));
  d = max(d, __shfl_xor(d, 32));

  for (int i = 0; i < d; i += 4){
    int ee[4]; bool vv[4]; int ss[4]; float4 wv[4]; ushort4 uu[4];
    #pragma unroll
    for (int u = 0; u < 4; u++){
      ee[u] = rb + i + u; vv[u] = ee[u] < re;
      int ec = vv[u] ? ee[u] : (re - 1);
      ss[u] = col[ec];
      wv[u] = *(const float4*)(w + (size_t)ec*4);
      uu[u] = *(const ushort4*)(hb + (size_t)ss[u]*64 + q*4);
    }
    #pragma unroll
    for (int u = 0; u < 4; u++){
      if (vv[u]){
        float y0 = b2f(uu[u].x), y1 = b2f(uu[u].y), y2 = b2f(uu[u].z), y3 = b2f(uu[u].w);
        acc[0][0] += wv[u].x*y0; acc[0][1] += wv[u].x*y1; acc[0][2] += wv[u].x*y2; acc[0][3] += wv[u].x*y3;
        acc[1][0] += wv[u].y*y0; acc[1][1] += wv[u].y*y1; acc[1][2] += wv[u].y*y2; acc[1][3] += wv[u].y*y3;
        acc[2][0] += wv[u].z*y0; acc[2][1] += wv[u].z*y1; acc[2][2] += wv[u].z*y2; acc[2][3] += wv[u].z*y3;
        acc[3][0] += wv[u].w*y0; acc[3][1] += wv[u].w*y1; acc[3][2] += wv[u].w*y2; acc[3][3] += wv[u].w*y3;
      }
    }
  }

  #pragma unroll
  for (int h = 0; h < 4; h++){
    float wih = (h==0)?wi4.x:(h==1)?wi4.y:(h==2)?wi4.z:wi4.w;
    ushort4 o = { f2b(acc[h][0]*wih), f2b(acc[h][1]*wih), f2b(acc[h][2]*wih), f2b(acc[h][3]*wih) };
    *(ushort4*)(aggb + (size_t)node*256 + h*64 + q*4) = o;
  }
}

// ---------------- layer-0 transform (f32, VALU) + epilogue + layer-1 logits ----------------
__global__ __launch_bounds__(256, 4) void k_gemmB36(const float* __restrict__ agg, const float* __restrict__ Ws,
    const float* __restrict__ bias, const float* __restrict__ gma, const float* __restrict__ bta,
    const float* __restrict__ mea, const float* __restrict__ var,
    float* __restrict__ hout, unsigned short* __restrict__ hbf,
    const float* __restrict__ WaN, float* __restrict__ lg){
  __shared__ float xs[64*68];
  __shared__ float ws[64*68];
  __shared__ float wal[512];
  int t = threadIdx.x;
  int base = blockIdx.x * 64;
  int r = t >> 4, c2 = t & 15;
  for (int i = t; i < 512; i += 256) wal[i] = WaN[i];

  for (int i = t; i < 64*9; i += 256){
    int nd = i / 9, kk = i - nd*9;
    float4 v = {0.f,0.f,0.f,0.f};
    if (base + nd < NN) v = *(const float4*)(agg + (size_t)(base+nd)*36 + kk*4);
    *(float4*)(xs + nd*44 + kk*4) = v;
  }
  for (int i = t; i < 36*16; i += 256){
    int k = i >> 4, c4 = i & 15;
    *(float4*)(ws + k*68 + c4*4) = *(const float4*)(Ws + (size_t)k*64 + c4*4);
  }
  __syncthreads();

  float acc[4][4];
  #pragma unroll
  for (int i = 0; i < 4; i++)
    #pragma unroll
    for (int u = 0; u < 4; u++) acc[i][u] = 0.f;

  #pragma unroll 2
  for (int k4 = 0; k4 < 36; k4 += 4){
    float4 xv[4], wv[4];
    #pragma unroll
    for (int i = 0; i < 4; i++) xv[i] = *(const float4*)(xs + (4*r+i)*44 + k4);
    #pragma unroll
    for (int u = 0; u < 4; u++) wv[u] = *(const float4*)(ws + (k4+u)*68 + 4*c2);
    #pragma unroll
    for (int i = 0; i < 4; i++){
      float xr[4] = {xv[i].x, xv[i].y, xv[i].z, xv[i].w};
      #pragma unroll
      for (int u = 0; u < 4; u++){
        acc[i][0] += xr[u]*wv[u].x; acc[i][1] += xr[u]*wv[u].y;
        acc[i][2] += xr[u]*wv[u].z; acc[i][3] += xr[u]*wv[u].w;
      }
    }
  }

  __syncthreads();
  int cb = 4*c2;
  float4 bi = *(const float4*)(bias + cb);
  float4 gm = *(const float4*)(gma + cb);
  float4 bt = *(const float4*)(bta + cb);
  float4 me = *(const float4*)(mea + cb);
  float4 va = *(const float4*)(var + cb);
  float sc0 = rsqrtf(va.x + 1e-5f)*gm.x, sc1 = rsqrtf(va.y + 1e-5f)*gm.y;
  float sc2 = rsqrtf(va.z + 1e-5f)*gm.z, sc3 = rsqrtf(va.w + 1e-5f)*gm.w;
  #pragma unroll
  for (int i = 0; i < 4; i++){
    int node = base + 4*r + i;
    if (node < NN){
      float o0 = (acc[i][0] + bi.x - me.x)*sc0 + bt.x;
      float o1 = (acc[i][1] + bi.y - me.y)*sc1 + bt.y;
      float o2 = (acc[i][2] + bi.z - me.z)*sc2 + bt.z;
      float o3 = (acc[i][3] + bi.w - me.w)*sc3 + bt.w;
      o0 = o0 > 0.f ? o0 : (__expf(o0) - 1.f);
      o1 = o1 > 0.f ? o1 : (__expf(o1) - 1.f);
      o2 = o2 > 0.f ? o2 : (__expf(o2) - 1.f);
      o3 = o3 > 0.f ? o3 : (__expf(o3) - 1.f);
      float4 st = {o0, o1, o2, o3};
      *(float4*)(hout + (size_t)node*64 + cb) = st;
      uint2 pb = { (unsigned)f2b(o0) | ((unsigned)f2b(o1) << 16),
                   (unsigned)f2b(o2) | ((unsigned)f2b(o3) << 16) };
      *(uint2*)(hbf + (size_t)node*64 + cb) = pb;
      *(float4*)(xs + (4*r+i)*68 + cb) = st;
    }
  }
  __syncthreads();
  int nd = t >> 2, jq = (t & 3) * 2;
  int node = base + nd;
  if (node < NN){
    float s0 = 0.f, s1 = 0.f;
    #pragma unroll 4
    for (int k = 0; k < 64; k += 4){
      float4 xv = *(const float4*)(xs + nd*68 + k);
      const float* w0 = wal + k*8 + jq;
      s0 += xv.x*w0[0] + xv.y*w0[8] + xv.z*w0[16] + xv.w*w0[24];
      s1 += xv.x*w0[1] + xv.y*w0[9] + xv.z*w0[17] + xv.w*w0[25];
    }
    float2 sv = {s0, s1};
    *(float2*)(lg + (size_t)node*8 + jq) = sv;
  }
}

// ---------------- layers 1-3 transform: MFMA with W staged in LDS (192 nodes/block) ----------------
// Barrier-drain fix: A-fragment loads issued AFTER the staging barrier so the
// s_waitcnt vmcnt(0) before s_barrier drains only the L2-hot W stage; the A gather
// then overlaps the MFMA/ds_read chain via fine-grained per-use vmcnt waits.
template<bool LOGITS>
__global__ __launch_bounds__(768, 6) void k_gemmBM(const unsigned short* __restrict__ aggb,
    const unsigned short* __restrict__ Wfhi, const unsigned short* __restrict__ Wflo,
    const float* __restrict__ bias, const float* __restrict__ gma, const float* __restrict__ bta,
    const float* __restrict__ mea, const float* __restrict__ var,
    const float* __restrict__ hres, float* __restrict__ hout, unsigned short* __restrict__ hbf,
    const float* __restrict__ WaN, float* __restrict__ lg){
  __shared__ unsigned short wbuf[32768];   // 64KB: Whi | Wlo; reused as df[192][68] f32
  __shared__ float wal[512];
  int t = threadIdx.x, lane = t & 63, wv = t >> 6;
  int base = blockIdx.x * 192;
  if (LOGITS && t < 512) wal[t] = WaN[t];

  // stage W: 2048+2048 uint4, 768 threads
  {
    uint4* wb = (uint4*)wbuf;
    const uint4* gh = (const uint4*)Wfhi;
    const uint4* gl = (const uint4*)Wflo;
    for (int i = t; i < 2048; i += 768) wb[i] = gh[i];
    for (int i = t; i < 2048; i += 768) wb[2048 + i] = gl[i];
  }
  __syncthreads();    // drains only the W stage (L2-hot)

  // A fragments from global — issued after the barrier, overlapping the MFMA loop
  int anode = base + (wv << 4) + (lane & 15);
  if (anode >= NN) anode = NN - 1;
  const unsigned short* ap = aggb + (size_t)anode*256 + ((lane >> 4) << 3);
  bf16x8 af[8];
  #pragma unroll
  for (int s = 0; s < 8; s++) af[s] = *(const bf16x8*)(ap + s*32);

  f32x4 acch[4], accl[4];
  #pragma unroll
  for (int c = 0; c < 4; c++){ acch[c] = (f32x4)0.f; accl[c] = (f32x4)0.f; }

  #pragma unroll
  for (int s = 0; s < 8; s++){
    #pragma unroll
    for (int c = 0; c < 4; c++){
      int fidx = ((c*8 + s)*64 + lane)*8;
      bf16x8 bh = *(const bf16x8*)(wbuf + fidx);
      bf16x8 bl = *(const bf16x8*)(wbuf + 16384 + fidx);
      acch[c] = __builtin_amdgcn_mfma_f32_16x16x32_bf16(af[s], bh, acch[c], 0, 0, 0);
      accl[c] = __builtin_amdgcn_mfma_f32_16x16x32_bf16(af[s], bl, accl[c], 0, 0, 0);
    }
  }
  __syncthreads();   // all W reads done; wbuf now reusable as df

  float* df = (float*)wbuf;   // [192][68] = 52224 B <= 65536 B
  {
    int rr = (wv << 4) + ((lane >> 4) << 2);
    int cc = lane & 15;
    #pragma unroll
    for (int c = 0; c < 4; c++)
      #pragma unroll
      for (int r = 0; r < 4; r++)
        df[(rr + r)*68 + (c << 4) + cc] = acch[c][r] + accl[c][r];
  }
  __syncthreads();

  // epilogue: bias + BN + ELU + residual (wave's own 16 nodes, j = lane)
  {
    int j = lane;
    float bi = bias[j], bt2 = bta[j], me = mea[j];
    float sc = rsqrtf(var[j] + 1e-5f) * gma[j];
    #pragma unroll 4
    for (int it = 0; it < 16; it++){
      int nd = (wv << 4) + it;
      int node = base + nd;
      if (node < NN){
        float o = df[nd*68 + j] + bi;
        o = (o - me)*sc + bt2;
        o = o > 0.f ? o : (__expf(o) - 1.f);
        o += hres[(size_t)node*64 + j];
        hout[(size_t)node*64 + j] = o;
        if (LOGITS){
          hbf[(size_t)node*64 + j] = f2b(o);
          df[nd*68 + j] = o;
        }
      }
    }
  }
  if (LOGITS){
    __syncthreads();
    int nd = t >> 2, jq = (t & 3) * 2;       // 768 threads -> 192 nodes x 2 j-pairs
    int node = base + nd;
    if (node < NN){
      float s0 = 0.f, s1 = 0.f;
      #pragma unroll 4
      for (int k = 0; k < 64; k += 4){
        float4 xv = *(const float4*)(df + nd*68 + k);
        const float* w0 = wal + k*8 + jq;
        s0 += xv.x*w0[0] + xv.y*w0[8] + xv.z*w0[16] + xv.w*w0[24];
        s1 += xv.x*w0[1] + xv.y*w0[9] + xv.z*w0[17] + xv.w*w0[25];
      }
      float2 sv = {s0, s1};
      *(float2*)(lg + (size_t)node*8 + jq) = sv;
    }
  }
}

// ---------------- pooling ----------------
__global__ __launch_bounds__(64) void k_pool(const float* __restrict__ h, const int* __restrict__ gstart,
                                             float* __restrict__ pooled){
  int g = blockIdx.x; int lane = threadIdx.x;
  int beg = gstart[g], end = gstart[g+1];
  float acc = 0.f;
  for (int n = beg; n < end; n++) acc += h[(size_t)n*64 + lane];
  float cnt = (float)(end - beg);
  pooled[(size_t)g*64 + lane] = acc / fmaxf(cnt, 1.f);
}

// ---------------- output MLP (wave per graph) ----------------
__global__ __launch_bounds__(256) void k_mlp(const float* __restrict__ pooled, const float* __restrict__ W1,
                                             const float* __restrict__ b1, const float* __restrict__ W2,
                                             const float* __restrict__ b2, float* __restrict__ out){
  int g = (blockIdx.x*256 + threadIdx.x) >> 6;
  int lane = threadIdx.x & 63;
  if (g >= GG) return;
  float pv = pooled[(size_t)g*64 + lane];
  int j = lane & 31, half = lane >> 5;
  float z = half ? 0.f : b1[j];
  #pragma unroll
  for (int c = 0; c < 32; c++){
    int cc = half*32 + c;
    z += __shfl(pv, cc) * W1[cc*32 + j];
  }
  z += __shfl_xor(z, 32);
  float o = 0.f;
  if (half == 0){
    z = z > 0.f ? z : (__expf(z) - 1.f);
    o = z * W2[j];
  }
  o += __shfl_xor(o, 1); o += __shfl_xor(o, 2); o += __shfl_xor(o, 4);
  o += __shfl_xor(o, 8); o += __shfl_xor(o, 16);
  if (lane == 0) out[g] = o + b2[0];
}

extern "C" void kernel_launch(void* const* d_in, const int* in_sizes, int n_in,
                              void* d_out, int out_size, void* d_ws, size_t ws_size,
                              hipStream_t stream) {
  const float* x    = (const float*)d_in[0];
  const int*   ei   = (const int*)d_in[1];
  const int*   batch= (const int*)d_in[2];
  const float* g0W  = (const float*)d_in[3];
  const float* g0as = (const float*)d_in[4];
  const float* g0ad = (const float*)d_in[5];
  const float* g0b  = (const float*)d_in[6];
  const float* bn0g = (const float*)d_in[7];
  const float* bn0b = (const float*)d_in[8];
  const float* bn0m = (const float*)d_in[9];
  const float* bn0v = (const float*)d_in[10];
  const float* gW   = (const float*)d_in[11];
  const float* gas  = (const float*)d_in[12];
  const float* gad  = (const float*)d_in[13];
  const float* gb   = (const float*)d_in[14];
  const float* bng  = (const float*)d_in[15];
  const float* bnb  = (const float*)d_in[16];
  const float* bnm  = (const float*)d_in[17];
  const float* bnv  = (const float*)d_in[18];
  const float* W1   = (const float*)d_in[19];
  const float* b1   = (const float*)d_in[20];
  const float* W2   = (const float*)d_in[21];
  const float* b2   = (const float*)d_in[22];
  float* out = (float*)d_out;
  (void)in_sizes; (void)n_in; (void)out_size; (void)ws_size;

  char* base = (char*)d_ws; size_t off = 0;
  auto alloc = [&](size_t b)->void*{ void* p = base + off; off = (off + b + 255) & ~(size_t)255; return p; };
  unsigned short* aggb = (unsigned short*)alloc((size_t)NN*256*2);  // 76.8 MB
  float* agg32  = (float*)alloc((size_t)NN*36*4);                   // 21.6 MB
  float* h_cur  = (float*)alloc((size_t)NN*64*4);                   // 38.4 MB
  unsigned short* hbf = (unsigned short*)alloc((size_t)NN*64*2);    // 19.2 MB
  float* lg     = (float*)alloc((size_t)NN*8*4);                    // 4.8 MB
  float* wE     = (float*)alloc((size_t)EE*4*4);                    // 9.6 MB
  float* wS     = (float*)alloc((size_t)NN*4*4);                    // 2.4 MB
  float* wI     = (float*)alloc((size_t)NN*4*4);                    // 2.4 MB
  int*   deg    = (int*)alloc((size_t)NN*4);
  int*   fill   = (int*)alloc((size_t)NN*4);
  int*   rp     = (int*)alloc((size_t)(NN+1)*4);
  int*   col    = (int*)alloc((size_t)EE*4);
  int*   bsum   = (int*)alloc(1024*4);
  int*   gstart = (int*)alloc((size_t)(GG+1)*4);
  float* pooled = (float*)alloc((size_t)GG*64*4);
  float* Wa0    = (float*)alloc((size_t)72*4);
  float* Wa     = (float*)alloc((size_t)1536*4);
  float* Wstk0  = (float*)alloc((size_t)2304*4);
  unsigned short* Wfhi = (unsigned short*)alloc((size_t)3*16384*2);
  unsigned short* Wflo = (unsigned short*)alloc((size_t)3*16384*2);

  const int* esrc = ei;
  const int* edst = ei + EE;

  hipMemsetAsync(deg, 0, (size_t)NN*4, stream);
  hipMemsetAsync(fill, 0, (size_t)NN*4, stream);

  int nb1 = (NN + 255)/256;
  k_count<<<(EE+255)/256, 256, 0, stream>>>(edst, deg);
  k_scan1<<<nb1, 256, 0, stream>>>(deg, rp, bsum);
  k_scan2<<<1, 1024, 0, stream>>>(bsum, nb1);
  k_scan3<<<nb1, 256, 0, stream>>>(rp, bsum);
  k_fill<<<(EE+255)/256, 256, 0, stream>>>(esrc, edst, rp, fill, col);
  k_gstart<<<(GG+256)/256, 256, 0, stream>>>(batch, gstart);
  k_fold<<<16, 256, 0, stream>>>(g0W, g0as, g0ad, gW, gas, gad, Wa0, Wa, Wstk0);
  k_foldB<<<24, 256, 0, stream>>>(gW, Wfhi, Wflo);

  int nlog  = (NN*8 + 255)/256;   // 4688
  int n4b   = (NN + 15)/16;       // 9375  (4 nodes per wave, 16 per block)
  int ngB   = (NN + 63)/64;       // 2344
  int ngBM  = (NN + 191)/192;     // 782
  int nnrm  = (NN*4 + 255)/256;   // 2344

  // layer 0 (layer-1 logits fused into gemmB36 via WaN = Wa[0])
  k_logits9<<<nlog, 256, 0, stream>>>(x, Wa0, lg);
  k_wgt<<<nnrm, 256, 0, stream>>>(lg, rp, col, wE, wS, wI);
  k_agg4f<<<n4b, 256, 0, stream>>>(x, wE, wS, wI, rp, col, agg32);
  k_gemmB36<<<ngB, 256, 0, stream>>>(agg32, Wstk0, g0b, bn0g, bn0b, bn0m, bn0v,
                                     h_cur, hbf, Wa, lg);
  // layers 1..3 (split agg + MFMA with LDS-staged W)
  for (int i = 0; i < 3; i++){
    k_wgt<<<nnrm, 256, 0, stream>>>(lg, rp, col, wE, wS, wI);
    k_agg4b<<<n4b, 256, 0, stream>>>(hbf, wE, wS, wI, rp, col, aggb);
    if (i < 2)
      k_gemmBM<true><<<ngBM, 768, 0, stream>>>(aggb, Wfhi + (size_t)i*16384, Wflo + (size_t)i*16384,
                                               gb + (size_t)i*64,
                                               bng + (size_t)i*64, bnb + (size_t)i*64,
                                               bnm + (size_t)i*64, bnv + (size_t)i*64,
                                               h_cur, h_cur, hbf, Wa + (size_t)(i+1)*512, lg);
    else
      k_gemmBM<false><<<ngBM, 768, 0, stream>>>(aggb, Wfhi + (size_t)i*16384, Wflo + (size_t)i*16384,
                                                gb + (size_t)i*64,
                                                bng + (size_t)i*64, bnb + (size_t)i*64,
                                                bnm + (size_t)i*64, bnv + (size_t)i*64,
                                                h_cur, h_cur, hbf, nullptr, nullptr);
  }

  k_pool<<<GG, 64, 0, stream>>>(h_cur, gstart, pooled);
  k_mlp<<<(GG*64 + 255)/256, 256, 0, stream>>>(pooled, W1, b1, W2, b2, out);
}